// Round 1
// baseline (434.025 us; speedup 1.0000x reference)
//
#include <hip/hip_runtime.h>
#include <hip/hip_bf16.h>

// AttentionBlock: groupnorm -> qkv conv1x1 -> MHA (8 heads, hd=64) -> proj -> residual
// B=16, C=512, H=W=32 (HW=1024). All GEMM-shaped work in bf16 MFMA 16x16x32, fp32 accum.

typedef __bf16 bf16;
typedef __attribute__((ext_vector_type(8))) __bf16 bf16x8;
typedef __attribute__((ext_vector_type(4))) float f32x4;

__device__ __forceinline__ bf16x8 ld8(const bf16* p) {
    return *reinterpret_cast<const bf16x8*>(p);
}

// ---------------- weight fp32 -> bf16 ----------------
__global__ __launch_bounds__(256) void cvt_fp32_bf16(const float* __restrict__ src,
                                                     bf16* __restrict__ dst, int n) {
    int i = (blockIdx.x * blockDim.x + threadIdx.x) * 4;
    int stride = gridDim.x * blockDim.x * 4;
    for (; i < n; i += stride) {
        float4 f = *reinterpret_cast<const float4*>(src + i);
        dst[i + 0] = (bf16)f.x;
        dst[i + 1] = (bf16)f.y;
        dst[i + 2] = (bf16)f.z;
        dst[i + 3] = (bf16)f.w;
    }
}

// ---------------- groupnorm stats: one block per (b,g) ----------------
// group g covers channels [g*64,(g+1)*64): 64*1024 = 65536 contiguous floats.
__global__ __launch_bounds__(256) void gn_stats(const float* __restrict__ x,
                                                float2* __restrict__ stats) {
    int bg = blockIdx.x;
    const float* base = x + (size_t)bg * 65536;
    float s = 0.f, sq = 0.f;
    for (int i = threadIdx.x * 4; i < 65536; i += 256 * 4) {
        float4 f = *reinterpret_cast<const float4*>(base + i);
        s += f.x + f.y + f.z + f.w;
        sq += f.x * f.x + f.y * f.y + f.z * f.z + f.w * f.w;
    }
    #pragma unroll
    for (int off = 32; off > 0; off >>= 1) {
        s += __shfl_down(s, off);
        sq += __shfl_down(sq, off);
    }
    __shared__ float ls[4], lq[4];
    int wave = threadIdx.x >> 6, lane = threadIdx.x & 63;
    if (lane == 0) { ls[wave] = s; lq[wave] = sq; }
    __syncthreads();
    if (threadIdx.x == 0) {
        s = ls[0] + ls[1] + ls[2] + ls[3];
        sq = lq[0] + lq[1] + lq[2] + lq[3];
        float mean = s * (1.f / 65536.f);
        float var = sq * (1.f / 65536.f) - mean * mean;
        stats[bg] = make_float2(mean, rsqrtf(var + 1e-5f));
    }
}

// ---------------- groupnorm apply + transpose: hnT[b][p][c] bf16 ----------------
__global__ __launch_bounds__(256) void gn_apply_t(const float* __restrict__ x,
                                                  const float* __restrict__ gamma,
                                                  const float* __restrict__ beta,
                                                  const float2* __restrict__ stats,
                                                  bf16* __restrict__ hnT) {
    int b = blockIdx.z, ct = blockIdx.y, pt = blockIdx.x;
    __shared__ float tile[64][65];
    int t = threadIdx.x;
    const float* xb = x + ((size_t)b * 512 + ct * 64) * 1024 + pt * 64;
    #pragma unroll
    for (int r = 0; r < 16; r++) {
        int cl = r * 4 + (t >> 6);
        int pl = t & 63;
        tile[cl][pl] = xb[(size_t)cl * 1024 + pl];
    }
    __syncthreads();
    float2 mr = stats[b * 8 + ct];   // c-tile == group (both 64 wide)
    int cl = t & 63;
    float g = gamma[ct * 64 + cl], be = beta[ct * 64 + cl];
    bf16* ob = hnT + ((size_t)b * 1024 + pt * 64) * 512 + ct * 64;
    #pragma unroll
    for (int r = 0; r < 16; r++) {
        int pl = r * 4 + (t >> 6);
        float v = (tile[cl][pl] - mr.x) * mr.y * g + be;
        ob[(size_t)pl * 512 + cl] = (bf16)v;
    }
}

// ---------------- NT GEMM core: D[m][n] = sum_k A[m][k] * Bm[n][k] ----------------
// 4 waves, 2x2 wave grid, 64x64 per wave, 128x128 per block, K unrolled by 32.
template <int KTOT>
__device__ __forceinline__ void gemm_core(const bf16* __restrict__ A,
                                          const bf16* __restrict__ Bm,
                                          int lda, int ldb,
                                          int m_base, int n_base, int lane,
                                          f32x4 (&acc)[4][4]) {
    int mrow = m_base + (lane & 15);
    int nrow = n_base + (lane & 15);
    int koff = (lane >> 4) * 8;
    for (int kk = 0; kk < KTOT; kk += 32) {
        bf16x8 a[4], bb[4];
        #pragma unroll
        for (int mf = 0; mf < 4; mf++)
            a[mf] = ld8(A + (size_t)(mrow + mf * 16) * lda + kk + koff);
        #pragma unroll
        for (int nf = 0; nf < 4; nf++)
            bb[nf] = ld8(Bm + (size_t)(nrow + nf * 16) * ldb + kk + koff);
        #pragma unroll
        for (int mf = 0; mf < 4; mf++)
            #pragma unroll
            for (int nf = 0; nf < 4; nf++)
                acc[mf][nf] = __builtin_amdgcn_mfma_f32_16x16x32_bf16(
                    a[mf], bb[nf], acc[mf][nf], 0, 0, 0);
    }
}

// qk_t[b][p][o] = sum_c hnT[b][p][c] * wqkv[o][c] + qkv_b[o], o in [0,1024)
__global__ __launch_bounds__(256) void gemm_qk(const bf16* __restrict__ hnT,
                                               const bf16* __restrict__ wqkv,
                                               const float* __restrict__ qkv_b,
                                               bf16* __restrict__ qk_t) {
    int b = blockIdx.z;
    int wave = threadIdx.x >> 6, lane = threadIdx.x & 63;
    int m_base = blockIdx.x * 128 + (wave >> 1) * 64;  // p
    int n_base = blockIdx.y * 128 + (wave & 1) * 64;   // o
    const bf16* A = hnT + (size_t)b * 1024 * 512;
    f32x4 acc[4][4] = {};
    gemm_core<512>(A, wqkv, 512, 512, m_base, n_base, lane, acc);
    bf16* out = qk_t + (size_t)b * 1024 * 1024;
    int col0 = n_base + (lane & 15);
    int row0 = m_base + (lane >> 4) * 4;
    #pragma unroll
    for (int nf = 0; nf < 4; nf++) {
        float bias = qkv_b[col0 + nf * 16];
        #pragma unroll
        for (int mf = 0; mf < 4; mf++)
            #pragma unroll
            for (int r = 0; r < 4; r++)
                out[(size_t)(row0 + mf * 16 + r) * 1024 + col0 + nf * 16] =
                    (bf16)(acc[mf][nf][r] + bias);
    }
}

// vbuf[b][o][p] = sum_c wv[o][c] * hnT[b][p][c] + qkv_b[1024+o], o in [0,512)
__global__ __launch_bounds__(256) void gemm_v(const bf16* __restrict__ wv,
                                              const bf16* __restrict__ hnT,
                                              const float* __restrict__ qkv_b,
                                              bf16* __restrict__ vbuf) {
    int b = blockIdx.z;
    int wave = threadIdx.x >> 6, lane = threadIdx.x & 63;
    int m_base = blockIdx.x * 128 + (wave >> 1) * 64;  // o
    int n_base = blockIdx.y * 128 + (wave & 1) * 64;   // p
    const bf16* Bm = hnT + (size_t)b * 1024 * 512;
    f32x4 acc[4][4] = {};
    gemm_core<512>(wv, Bm, 512, 512, m_base, n_base, lane, acc);
    bf16* out = vbuf + (size_t)b * 512 * 1024;
    int col0 = n_base + (lane & 15);
    int row0 = m_base + (lane >> 4) * 4;
    #pragma unroll
    for (int mf = 0; mf < 4; mf++)
        #pragma unroll
        for (int r = 0; r < 4; r++) {
            float bias = qkv_b[1024 + row0 + mf * 16 + r];
            #pragma unroll
            for (int nf = 0; nf < 4; nf++)
                out[(size_t)(row0 + mf * 16 + r) * 1024 + col0 + nf * 16] =
                    (bf16)(acc[mf][nf][r] + bias);
        }
}

// out[b][o][i] = sum_c wproj[o][c] * attnT[b][i][c] + proj_b[o] + x[b][o][i]
__global__ __launch_bounds__(256) void gemm_proj(const bf16* __restrict__ wproj,
                                                 const bf16* __restrict__ attnT,
                                                 const float* __restrict__ proj_b,
                                                 const float* __restrict__ x,
                                                 float* __restrict__ out) {
    int b = blockIdx.z;
    int wave = threadIdx.x >> 6, lane = threadIdx.x & 63;
    int m_base = blockIdx.x * 128 + (wave >> 1) * 64;  // o
    int n_base = blockIdx.y * 128 + (wave & 1) * 64;   // i
    const bf16* Bm = attnT + (size_t)b * 1024 * 512;
    f32x4 acc[4][4] = {};
    gemm_core<512>(wproj, Bm, 512, 512, m_base, n_base, lane, acc);
    const float* xb = x + (size_t)b * 512 * 1024;
    float* ob = out + (size_t)b * 512 * 1024;
    int col0 = n_base + (lane & 15);
    int row0 = m_base + (lane >> 4) * 4;
    #pragma unroll
    for (int mf = 0; mf < 4; mf++)
        #pragma unroll
        for (int r = 0; r < 4; r++) {
            int row = row0 + mf * 16 + r;
            float bias = proj_b[row];
            #pragma unroll
            for (int nf = 0; nf < 4; nf++) {
                size_t idx = (size_t)row * 1024 + col0 + nf * 16;
                ob[idx] = acc[mf][nf][r] + bias + xb[idx];
            }
        }
}

// ---------------- flash attention per (b, h, 64-query tile) ----------------
// qk_t[b][p][o]: o<512 -> q, o>=512 -> k (per head 64 contiguous cols). vbuf[b][c][j].
// Writes attnT[b][i][c] (c = h*64 + local), i.e. O^T, which proj consumes K-contiguously.
__global__ __launch_bounds__(256) void attn_kernel(const bf16* __restrict__ qk_t,
                                                   const bf16* __restrict__ vbuf,
                                                   bf16* __restrict__ attnT) {
    int b = blockIdx.z, h = blockIdx.y, it = blockIdx.x;
    int wave = threadIdx.x >> 6, lane = threadIdx.x & 63;
    int i0 = it * 64 + wave * 16;
    const bf16* qkb = qk_t + (size_t)b * 1024 * 1024;
    const bf16* vb = vbuf + ((size_t)b * 512 + h * 64) * 1024;
    int koff = (lane >> 4) * 8;

    bf16x8 aq[2];
    #pragma unroll
    for (int kc = 0; kc < 2; kc++)
        aq[kc] = ld8(qkb + (size_t)(i0 + (lane & 15)) * 1024 + h * 64 + kc * 32 + koff);

    float m_run[4], l_run[4];
    f32x4 oacc[4] = {};
    #pragma unroll
    for (int r = 0; r < 4; r++) { m_run[r] = -INFINITY; l_run[r] = 0.f; }

    __shared__ __align__(16) bf16 P_lds[4][16][72];  // per-wave, +8 pad

    for (int j0 = 0; j0 < 1024; j0 += 64) {
        f32x4 s[4] = {};
        #pragma unroll
        for (int kc = 0; kc < 2; kc++) {
            bf16x8 kf[4];
            #pragma unroll
            for (int jf = 0; jf < 4; jf++)
                kf[jf] = ld8(qkb + (size_t)(j0 + jf * 16 + (lane & 15)) * 1024 +
                             512 + h * 64 + kc * 32 + koff);
            #pragma unroll
            for (int jf = 0; jf < 4; jf++)
                s[jf] = __builtin_amdgcn_mfma_f32_16x16x32_bf16(aq[kc], kf[jf], s[jf], 0, 0, 0);
        }
        // online softmax over j (rows = (lane>>4)*4+r, cols spread over lane&15 x 4 frags)
        float corr[4];
        #pragma unroll
        for (int r = 0; r < 4; r++) {
            #pragma unroll
            for (int jf = 0; jf < 4; jf++) s[jf][r] *= 0.125f;
            float mx = fmaxf(fmaxf(s[0][r], s[1][r]), fmaxf(s[2][r], s[3][r]));
            #pragma unroll
            for (int off = 1; off < 16; off <<= 1) mx = fmaxf(mx, __shfl_xor(mx, off));
            float mnew = fmaxf(m_run[r], mx);
            corr[r] = __expf(m_run[r] - mnew);
            float sum = 0.f;
            #pragma unroll
            for (int jf = 0; jf < 4; jf++) {
                float p = __expf(s[jf][r] - mnew);
                s[jf][r] = p;
                sum += p;
            }
            #pragma unroll
            for (int off = 1; off < 16; off <<= 1) sum += __shfl_xor(sum, off);
            l_run[r] = l_run[r] * corr[r] + sum;
            m_run[r] = mnew;
        }
        #pragma unroll
        for (int cf = 0; cf < 4; cf++)
            #pragma unroll
            for (int r = 0; r < 4; r++) oacc[cf][r] *= corr[r];
        // P (D-layout) -> LDS -> A-layout
        #pragma unroll
        for (int jf = 0; jf < 4; jf++)
            #pragma unroll
            for (int r = 0; r < 4; r++)
                P_lds[wave][(lane >> 4) * 4 + r][jf * 16 + (lane & 15)] = (bf16)s[jf][r];
        __syncthreads();
        #pragma unroll
        for (int ks = 0; ks < 2; ks++) {
            bf16x8 pa = ld8(&P_lds[wave][lane & 15][ks * 32 + koff]);
            #pragma unroll
            for (int cf = 0; cf < 4; cf++) {
                bf16x8 vf = ld8(vb + (size_t)(cf * 16 + (lane & 15)) * 1024 + j0 + ks * 32 + koff);
                oacc[cf] = __builtin_amdgcn_mfma_f32_16x16x32_bf16(pa, vf, oacc[cf], 0, 0, 0);
            }
        }
        __syncthreads();
    }
    bf16* ob = attnT + ((size_t)b * 1024 + i0 + (lane >> 4) * 4) * 512 + h * 64 + (lane & 15);
    #pragma unroll
    for (int r = 0; r < 4; r++) {
        float inv = 1.f / l_run[r];
        #pragma unroll
        for (int cf = 0; cf < 4; cf++)
            ob[(size_t)r * 512 + cf * 16] = (bf16)(oacc[cf][r] * inv);
    }
}

extern "C" void kernel_launch(void* const* d_in, const int* in_sizes, int n_in,
                              void* d_out, int out_size, void* d_ws, size_t ws_size,
                              hipStream_t stream) {
    (void)in_sizes; (void)n_in; (void)out_size; (void)ws_size;
    const float* x      = (const float*)d_in[0];
    const float* norm_w = (const float*)d_in[1];
    const float* norm_b = (const float*)d_in[2];
    const float* qkv_w  = (const float*)d_in[3];
    const float* qkv_b  = (const float*)d_in[4];
    const float* proj_w = (const float*)d_in[5];
    const float* proj_b = (const float*)d_in[6];
    float* out = (float*)d_out;

    // workspace layout (~86 MB)
    char* w = (char*)d_ws;
    bf16* wqkv  = (bf16*)w;                        // 1536*512
    bf16* wproj = wqkv + (size_t)1536 * 512;       // 512*512
    float2* stats = (float2*)(wproj + (size_t)512 * 512);  // 128
    bf16* hnT   = (bf16*)((char*)stats + 1024);    // [16][1024][512]
    bf16* qk_t  = hnT + (size_t)16 * 1024 * 512;   // [16][1024][1024]
    bf16* vbuf  = qk_t + (size_t)16 * 1024 * 1024; // [16][512][1024]
    bf16* attnT = vbuf + (size_t)16 * 512 * 1024;  // [16][1024][512]

    cvt_fp32_bf16<<<768, 256, 0, stream>>>(qkv_w, wqkv, 1536 * 512);
    cvt_fp32_bf16<<<256, 256, 0, stream>>>(proj_w, wproj, 512 * 512);
    gn_stats<<<128, 256, 0, stream>>>(x, stats);
    gn_apply_t<<<dim3(16, 8, 16), 256, 0, stream>>>(x, norm_w, norm_b, stats, hnT);
    gemm_qk<<<dim3(8, 8, 16), 256, 0, stream>>>(hnT, wqkv, qkv_b, qk_t);
    gemm_v<<<dim3(4, 8, 16), 256, 0, stream>>>(wqkv + (size_t)1024 * 512, hnT, qkv_b, vbuf);
    attn_kernel<<<dim3(16, 8, 16), 256, 0, stream>>>(qk_t, vbuf, attnT);
    gemm_proj<<<dim3(4, 8, 16), 256, 0, stream>>>(wproj, attnT, proj_b, x, out);
}

// Round 2
// 331.934 us; speedup vs baseline: 1.3076x; 1.3076x over previous
//
#include <hip/hip_runtime.h>
#include <hip/hip_bf16.h>

// AttentionBlock: groupnorm -> qkv conv1x1 -> MHA (8 heads, hd=64) -> proj -> residual
// B=16, C=512, H=W=32 (HW=1024). All GEMM-shaped work in bf16 MFMA 16x16x32, fp32 accum.

typedef __bf16 bf16;
typedef __attribute__((ext_vector_type(8))) __bf16 bf16x8;
typedef __attribute__((ext_vector_type(4))) float f32x4;

__device__ __forceinline__ bf16x8 ld8(const bf16* p) {
    return *reinterpret_cast<const bf16x8*>(p);
}

// ---------------- weight fp32 -> bf16 ----------------
__global__ __launch_bounds__(256) void cvt_fp32_bf16(const float* __restrict__ src,
                                                     bf16* __restrict__ dst, int n) {
    int i = (blockIdx.x * blockDim.x + threadIdx.x) * 4;
    int stride = gridDim.x * blockDim.x * 4;
    for (; i < n; i += stride) {
        float4 f = *reinterpret_cast<const float4*>(src + i);
        dst[i + 0] = (bf16)f.x;
        dst[i + 1] = (bf16)f.y;
        dst[i + 2] = (bf16)f.z;
        dst[i + 3] = (bf16)f.w;
    }
}

// ---------------- groupnorm stats: one block per (b,g) ----------------
__global__ __launch_bounds__(256) void gn_stats(const float* __restrict__ x,
                                                float2* __restrict__ stats) {
    int bg = blockIdx.x;
    const float* base = x + (size_t)bg * 65536;
    float s = 0.f, sq = 0.f;
    for (int i = threadIdx.x * 4; i < 65536; i += 256 * 4) {
        float4 f = *reinterpret_cast<const float4*>(base + i);
        s += f.x + f.y + f.z + f.w;
        sq += f.x * f.x + f.y * f.y + f.z * f.z + f.w * f.w;
    }
    #pragma unroll
    for (int off = 32; off > 0; off >>= 1) {
        s += __shfl_down(s, off);
        sq += __shfl_down(sq, off);
    }
    __shared__ float ls[4], lq[4];
    int wave = threadIdx.x >> 6, lane = threadIdx.x & 63;
    if (lane == 0) { ls[wave] = s; lq[wave] = sq; }
    __syncthreads();
    if (threadIdx.x == 0) {
        s = ls[0] + ls[1] + ls[2] + ls[3];
        sq = lq[0] + lq[1] + lq[2] + lq[3];
        float mean = s * (1.f / 65536.f);
        float var = sq * (1.f / 65536.f) - mean * mean;
        stats[bg] = make_float2(mean, rsqrtf(var + 1e-5f));
    }
}

// ---------------- groupnorm apply + transpose: hnT[b][p][c] bf16 ----------------
__global__ __launch_bounds__(256) void gn_apply_t(const float* __restrict__ x,
                                                  const float* __restrict__ gamma,
                                                  const float* __restrict__ beta,
                                                  const float2* __restrict__ stats,
                                                  bf16* __restrict__ hnT) {
    int b = blockIdx.z, ct = blockIdx.y, pt = blockIdx.x;
    __shared__ float tile[64][65];
    int t = threadIdx.x;
    const float* xb = x + ((size_t)b * 512 + ct * 64) * 1024 + pt * 64;
    #pragma unroll
    for (int r = 0; r < 16; r++) {
        int cl = r * 4 + (t >> 6);
        int pl = t & 63;
        tile[cl][pl] = xb[(size_t)cl * 1024 + pl];
    }
    __syncthreads();
    float2 mr = stats[b * 8 + ct];   // c-tile == group (both 64 wide)
    int cl = t & 63;
    float g = gamma[ct * 64 + cl], be = beta[ct * 64 + cl];
    bf16* ob = hnT + ((size_t)b * 1024 + pt * 64) * 512 + ct * 64;
    #pragma unroll
    for (int r = 0; r < 16; r++) {
        int pl = r * 4 + (t >> 6);
        float v = (tile[cl][pl] - mr.x) * mr.y * g + be;
        ob[(size_t)pl * 512 + cl] = (bf16)v;
    }
}

// ---------------- NT GEMM core: D[m][n] = sum_k A[m][k] * Bm[n][k] ----------------
template <int KTOT>
__device__ __forceinline__ void gemm_core(const bf16* __restrict__ A,
                                          const bf16* __restrict__ Bm,
                                          int lda, int ldb,
                                          int m_base, int n_base, int lane,
                                          f32x4 (&acc)[4][4]) {
    int mrow = m_base + (lane & 15);
    int nrow = n_base + (lane & 15);
    int koff = (lane >> 4) * 8;
    for (int kk = 0; kk < KTOT; kk += 32) {
        bf16x8 a[4], bb[4];
        #pragma unroll
        for (int mf = 0; mf < 4; mf++)
            a[mf] = ld8(A + (size_t)(mrow + mf * 16) * lda + kk + koff);
        #pragma unroll
        for (int nf = 0; nf < 4; nf++)
            bb[nf] = ld8(Bm + (size_t)(nrow + nf * 16) * ldb + kk + koff);
        #pragma unroll
        for (int mf = 0; mf < 4; mf++)
            #pragma unroll
            for (int nf = 0; nf < 4; nf++)
                acc[mf][nf] = __builtin_amdgcn_mfma_f32_16x16x32_bf16(
                    a[mf], bb[nf], acc[mf][nf], 0, 0, 0);
    }
}

// qk_t[b][p][o] = sum_c hnT[b][p][c] * wqkv[o][c] + qkv_b[o], o in [0,1024)
__global__ __launch_bounds__(256) void gemm_qk(const bf16* __restrict__ hnT,
                                               const bf16* __restrict__ wqkv,
                                               const float* __restrict__ qkv_b,
                                               bf16* __restrict__ qk_t) {
    int b = blockIdx.z;
    int wave = threadIdx.x >> 6, lane = threadIdx.x & 63;
    int m_base = blockIdx.x * 128 + (wave >> 1) * 64;  // p
    int n_base = blockIdx.y * 128 + (wave & 1) * 64;   // o
    const bf16* A = hnT + (size_t)b * 1024 * 512;
    f32x4 acc[4][4] = {};
    gemm_core<512>(A, wqkv, 512, 512, m_base, n_base, lane, acc);
    bf16* out = qk_t + (size_t)b * 1024 * 1024;
    int col0 = n_base + (lane & 15);
    int row0 = m_base + (lane >> 4) * 4;
    #pragma unroll
    for (int nf = 0; nf < 4; nf++) {
        float bias = qkv_b[col0 + nf * 16];
        #pragma unroll
        for (int mf = 0; mf < 4; mf++)
            #pragma unroll
            for (int r = 0; r < 4; r++)
                out[(size_t)(row0 + mf * 16 + r) * 1024 + col0 + nf * 16] =
                    (bf16)(acc[mf][nf][r] + bias);
    }
}

// vbuf[b][o][p] = sum_c wv[o][c] * hnT[b][p][c] + qkv_b[1024+o], o in [0,512)
__global__ __launch_bounds__(256) void gemm_v(const bf16* __restrict__ wv,
                                              const bf16* __restrict__ hnT,
                                              const float* __restrict__ qkv_b,
                                              bf16* __restrict__ vbuf) {
    int b = blockIdx.z;
    int wave = threadIdx.x >> 6, lane = threadIdx.x & 63;
    int m_base = blockIdx.x * 128 + (wave >> 1) * 64;  // o
    int n_base = blockIdx.y * 128 + (wave & 1) * 64;   // p
    const bf16* Bm = hnT + (size_t)b * 1024 * 512;
    f32x4 acc[4][4] = {};
    gemm_core<512>(wv, Bm, 512, 512, m_base, n_base, lane, acc);
    bf16* out = vbuf + (size_t)b * 512 * 1024;
    int col0 = n_base + (lane & 15);
    int row0 = m_base + (lane >> 4) * 4;
    #pragma unroll
    for (int mf = 0; mf < 4; mf++)
        #pragma unroll
        for (int r = 0; r < 4; r++) {
            float bias = qkv_b[1024 + row0 + mf * 16 + r];
            #pragma unroll
            for (int nf = 0; nf < 4; nf++)
                out[(size_t)(row0 + mf * 16 + r) * 1024 + col0 + nf * 16] =
                    (bf16)(acc[mf][nf][r] + bias);
        }
}

// out[b][o][i] = sum_c wproj[o][c] * attnT[b][i][c] + proj_b[o] + x[b][o][i]
__global__ __launch_bounds__(256) void gemm_proj(const bf16* __restrict__ wproj,
                                                 const bf16* __restrict__ attnT,
                                                 const float* __restrict__ proj_b,
                                                 const float* __restrict__ x,
                                                 float* __restrict__ out) {
    int b = blockIdx.z;
    int wave = threadIdx.x >> 6, lane = threadIdx.x & 63;
    int m_base = blockIdx.x * 128 + (wave >> 1) * 64;  // o
    int n_base = blockIdx.y * 128 + (wave & 1) * 64;   // i
    const bf16* Bm = attnT + (size_t)b * 1024 * 512;
    f32x4 acc[4][4] = {};
    gemm_core<512>(wproj, Bm, 512, 512, m_base, n_base, lane, acc);
    const float* xb = x + (size_t)b * 512 * 1024;
    float* ob = out + (size_t)b * 512 * 1024;
    int col0 = n_base + (lane & 15);
    int row0 = m_base + (lane >> 4) * 4;
    #pragma unroll
    for (int mf = 0; mf < 4; mf++)
        #pragma unroll
        for (int r = 0; r < 4; r++) {
            int row = row0 + mf * 16 + r;
            float bias = proj_b[row];
            #pragma unroll
            for (int nf = 0; nf < 4; nf++) {
                size_t idx = (size_t)row * 1024 + col0 + nf * 16;
                ob[idx] = acc[mf][nf][r] + bias + xb[idx];
            }
        }
}

// ---------------- flash attention ----------------
// Grid: 1024 blocks (flat), 4 waves/block, QBLK=32 rows per wave -> 128 queries/block.
// XCD-bijective swizzle: flat = [it 8][bh 128]; all 8 it-tiles of one (b,h) land on
// the same XCD (flat % 8 == bh % 8 under round-robin dispatch) -> K/V L2-resident.
// NO barriers: P_lds region is strictly per-wave; compiler-inserted lgkmcnt orders
// the LDS write->read within the wave.
__global__ __launch_bounds__(256, 3) void attn_kernel(const bf16* __restrict__ qk_t,
                                                      const bf16* __restrict__ vbuf,
                                                      bf16* __restrict__ attnT) {
    int flat = blockIdx.x;
    int it = flat >> 7;          // 0..7 (128-query tiles)
    int bh = flat & 127;
    int b = bh >> 3, h = bh & 7;
    int wave = threadIdx.x >> 6, lane = threadIdx.x & 63;
    int i0 = it * 128 + wave * 32;
    const bf16* qkb = qk_t + (size_t)b * 1024 * 1024;
    const bf16* vb = vbuf + ((size_t)b * 512 + h * 64) * 1024;
    int l15 = lane & 15;
    int koff = (lane >> 4) * 8;

    // Q fragments: 2 row-tiles of 16 x K=64
    bf16x8 aq[2][2];
    #pragma unroll
    for (int mi = 0; mi < 2; mi++)
        #pragma unroll
        for (int kc = 0; kc < 2; kc++)
            aq[mi][kc] = ld8(qkb + (size_t)(i0 + mi * 16 + l15) * 1024 + h * 64 + kc * 32 + koff);

    float m_run[2][4], l_run[2][4];
    f32x4 oacc[2][4] = {};
    #pragma unroll
    for (int mi = 0; mi < 2; mi++)
        #pragma unroll
        for (int r = 0; r < 4; r++) { m_run[mi][r] = -INFINITY; l_run[mi][r] = 0.f; }

    __shared__ __align__(16) bf16 P_lds[4][32][72];  // per-wave, +8 pad

    for (int j0 = 0; j0 < 1024; j0 += 64) {
        // ---- QK^T: 64 keys x 32 queries ----
        bf16x8 kf[4][2];
        #pragma unroll
        for (int jf = 0; jf < 4; jf++)
            #pragma unroll
            for (int kc = 0; kc < 2; kc++)
                kf[jf][kc] = ld8(qkb + (size_t)(j0 + jf * 16 + l15) * 1024 +
                                 512 + h * 64 + kc * 32 + koff);
        f32x4 s[2][4] = {};
        #pragma unroll
        for (int kc = 0; kc < 2; kc++)
            #pragma unroll
            for (int mi = 0; mi < 2; mi++)
                #pragma unroll
                for (int jf = 0; jf < 4; jf++)
                    s[mi][jf] = __builtin_amdgcn_mfma_f32_16x16x32_bf16(
                        aq[mi][kc], kf[jf][kc], s[mi][jf], 0, 0, 0);

        // ---- online softmax (rows = (lane>>4)*4+r within each mi tile) ----
        float corr[2][4];
        #pragma unroll
        for (int mi = 0; mi < 2; mi++)
            #pragma unroll
            for (int r = 0; r < 4; r++) {
                #pragma unroll
                for (int jf = 0; jf < 4; jf++) s[mi][jf][r] *= 0.125f;
                float mx = fmaxf(fmaxf(s[mi][0][r], s[mi][1][r]),
                                 fmaxf(s[mi][2][r], s[mi][3][r]));
                #pragma unroll
                for (int off = 1; off < 16; off <<= 1) mx = fmaxf(mx, __shfl_xor(mx, off));
                float mnew = fmaxf(m_run[mi][r], mx);
                corr[mi][r] = __expf(m_run[mi][r] - mnew);
                float sum = 0.f;
                #pragma unroll
                for (int jf = 0; jf < 4; jf++) {
                    float p = __expf(s[mi][jf][r] - mnew);
                    s[mi][jf][r] = p;
                    sum += p;
                }
                #pragma unroll
                for (int off = 1; off < 16; off <<= 1) sum += __shfl_xor(sum, off);
                l_run[mi][r] = l_run[mi][r] * corr[mi][r] + sum;
                m_run[mi][r] = mnew;
            }
        #pragma unroll
        for (int mi = 0; mi < 2; mi++)
            #pragma unroll
            for (int cf = 0; cf < 4; cf++)
                #pragma unroll
                for (int r = 0; r < 4; r++) oacc[mi][cf][r] *= corr[mi][r];

        // ---- P (D-layout) -> LDS -> A-layout (per-wave region, no barrier) ----
        #pragma unroll
        for (int mi = 0; mi < 2; mi++)
            #pragma unroll
            for (int jf = 0; jf < 4; jf++)
                #pragma unroll
                for (int r = 0; r < 4; r++)
                    P_lds[wave][mi * 16 + (lane >> 4) * 4 + r][jf * 16 + l15] =
                        (bf16)s[mi][jf][r];

        // ---- PV: oacc[mi][cf] += P[mi] * V[cf]^T ----
        #pragma unroll
        for (int ks = 0; ks < 2; ks++) {
            bf16x8 pa[2];
            pa[0] = ld8(&P_lds[wave][l15][ks * 32 + koff]);
            pa[1] = ld8(&P_lds[wave][16 + l15][ks * 32 + koff]);
            #pragma unroll
            for (int cf = 0; cf < 4; cf++) {
                bf16x8 vf = ld8(vb + (size_t)(cf * 16 + l15) * 1024 + j0 + ks * 32 + koff);
                oacc[0][cf] = __builtin_amdgcn_mfma_f32_16x16x32_bf16(pa[0], vf, oacc[0][cf], 0, 0, 0);
                oacc[1][cf] = __builtin_amdgcn_mfma_f32_16x16x32_bf16(pa[1], vf, oacc[1][cf], 0, 0, 0);
            }
        }
    }

    #pragma unroll
    for (int mi = 0; mi < 2; mi++) {
        bf16* ob = attnT + ((size_t)b * 1024 + i0 + mi * 16 + (lane >> 4) * 4) * 512 +
                   h * 64 + l15;
        #pragma unroll
        for (int r = 0; r < 4; r++) {
            float inv = 1.f / l_run[mi][r];
            #pragma unroll
            for (int cf = 0; cf < 4; cf++)
                ob[(size_t)r * 512 + cf * 16] = (bf16)(oacc[mi][cf][r] * inv);
        }
    }
}

extern "C" void kernel_launch(void* const* d_in, const int* in_sizes, int n_in,
                              void* d_out, int out_size, void* d_ws, size_t ws_size,
                              hipStream_t stream) {
    (void)in_sizes; (void)n_in; (void)out_size; (void)ws_size;
    const float* x      = (const float*)d_in[0];
    const float* norm_w = (const float*)d_in[1];
    const float* norm_b = (const float*)d_in[2];
    const float* qkv_w  = (const float*)d_in[3];
    const float* qkv_b  = (const float*)d_in[4];
    const float* proj_w = (const float*)d_in[5];
    const float* proj_b = (const float*)d_in[6];
    float* out = (float*)d_out;

    // workspace layout (~86 MB)
    char* w = (char*)d_ws;
    bf16* wqkv  = (bf16*)w;                        // 1536*512
    bf16* wproj = wqkv + (size_t)1536 * 512;       // 512*512
    float2* stats = (float2*)(wproj + (size_t)512 * 512);  // 128
    bf16* hnT   = (bf16*)((char*)stats + 1024);    // [16][1024][512]
    bf16* qk_t  = hnT + (size_t)16 * 1024 * 512;   // [16][1024][1024]
    bf16* vbuf  = qk_t + (size_t)16 * 1024 * 1024; // [16][512][1024]
    bf16* attnT = vbuf + (size_t)16 * 512 * 1024;  // [16][1024][512]

    cvt_fp32_bf16<<<768, 256, 0, stream>>>(qkv_w, wqkv, 1536 * 512);
    cvt_fp32_bf16<<<256, 256, 0, stream>>>(proj_w, wproj, 512 * 512);
    gn_stats<<<128, 256, 0, stream>>>(x, stats);
    gn_apply_t<<<dim3(16, 8, 16), 256, 0, stream>>>(x, norm_w, norm_b, stats, hnT);
    gemm_qk<<<dim3(8, 8, 16), 256, 0, stream>>>(hnT, wqkv, qkv_b, qk_t);
    gemm_v<<<dim3(4, 8, 16), 256, 0, stream>>>(wqkv + (size_t)1024 * 512, hnT, qkv_b, vbuf);
    attn_kernel<<<1024, 256, 0, stream>>>(qk_t, vbuf, attnT);
    gemm_proj<<<dim3(4, 8, 16), 256, 0, stream>>>(wproj, attnT, proj_b, x, out);
}

// Round 3
// 296.963 us; speedup vs baseline: 1.4615x; 1.1178x over previous
//
#include <hip/hip_runtime.h>
#include <hip/hip_bf16.h>

// AttentionBlock: groupnorm -> qkv conv1x1 -> MHA (8 heads, hd=64) -> proj -> residual
// B=16, C=512, H=W=32 (HW=1024). All GEMM-shaped work in bf16 MFMA 16x16x32, fp32 accum.

typedef __bf16 bf16;
typedef __attribute__((ext_vector_type(8))) __bf16 bf16x8;
typedef __attribute__((ext_vector_type(4))) float f32x4;

__device__ __forceinline__ bf16x8 ld8(const bf16* p) {
    return *reinterpret_cast<const bf16x8*>(p);
}

// ---------------- weight fp32 -> bf16 ----------------
__global__ __launch_bounds__(256) void cvt_fp32_bf16(const float* __restrict__ src,
                                                     bf16* __restrict__ dst, int n) {
    int i = (blockIdx.x * blockDim.x + threadIdx.x) * 4;
    int stride = gridDim.x * blockDim.x * 4;
    for (; i < n; i += stride) {
        float4 f = *reinterpret_cast<const float4*>(src + i);
        dst[i + 0] = (bf16)f.x;
        dst[i + 1] = (bf16)f.y;
        dst[i + 2] = (bf16)f.z;
        dst[i + 3] = (bf16)f.w;
    }
}

// ---------------- groupnorm stats: one block per (b,g) ----------------
__global__ __launch_bounds__(256) void gn_stats(const float* __restrict__ x,
                                                float2* __restrict__ stats) {
    int bg = blockIdx.x;
    const float* base = x + (size_t)bg * 65536;
    float s = 0.f, sq = 0.f;
    for (int i = threadIdx.x * 4; i < 65536; i += 256 * 4) {
        float4 f = *reinterpret_cast<const float4*>(base + i);
        s += f.x + f.y + f.z + f.w;
        sq += f.x * f.x + f.y * f.y + f.z * f.z + f.w * f.w;
    }
    #pragma unroll
    for (int off = 32; off > 0; off >>= 1) {
        s += __shfl_down(s, off);
        sq += __shfl_down(sq, off);
    }
    __shared__ float ls[4], lq[4];
    int wave = threadIdx.x >> 6, lane = threadIdx.x & 63;
    if (lane == 0) { ls[wave] = s; lq[wave] = sq; }
    __syncthreads();
    if (threadIdx.x == 0) {
        s = ls[0] + ls[1] + ls[2] + ls[3];
        sq = lq[0] + lq[1] + lq[2] + lq[3];
        float mean = s * (1.f / 65536.f);
        float var = sq * (1.f / 65536.f) - mean * mean;
        stats[bg] = make_float2(mean, rsqrtf(var + 1e-5f));
    }
}

// ---------------- groupnorm apply + transpose: hnT[b][p][c] bf16 ----------------
__global__ __launch_bounds__(256) void gn_apply_t(const float* __restrict__ x,
                                                  const float* __restrict__ gamma,
                                                  const float* __restrict__ beta,
                                                  const float2* __restrict__ stats,
                                                  bf16* __restrict__ hnT) {
    int b = blockIdx.z, ct = blockIdx.y, pt = blockIdx.x;
    __shared__ float tile[64][65];
    int t = threadIdx.x;
    const float* xb = x + ((size_t)b * 512 + ct * 64) * 1024 + pt * 64;
    #pragma unroll
    for (int r = 0; r < 16; r++) {
        int cl = r * 4 + (t >> 6);
        int pl = t & 63;
        tile[cl][pl] = xb[(size_t)cl * 1024 + pl];
    }
    __syncthreads();
    float2 mr = stats[b * 8 + ct];   // c-tile == group (both 64 wide)
    int cl = t & 63;
    float g = gamma[ct * 64 + cl], be = beta[ct * 64 + cl];
    bf16* ob = hnT + ((size_t)b * 1024 + pt * 64) * 512 + ct * 64;
    #pragma unroll
    for (int r = 0; r < 16; r++) {
        int pl = r * 4 + (t >> 6);
        float v = (tile[cl][pl] - mr.x) * mr.y * g + be;
        ob[(size_t)pl * 512 + cl] = (bf16)v;
    }
}

// ---------------- NT GEMM core: D[m][n] = sum_k A[m][k] * Bm[n][k] ----------------
template <int KTOT>
__device__ __forceinline__ void gemm_core(const bf16* __restrict__ A,
                                          const bf16* __restrict__ Bm,
                                          int lda, int ldb,
                                          int m_base, int n_base, int lane,
                                          f32x4 (&acc)[4][4]) {
    int mrow = m_base + (lane & 15);
    int nrow = n_base + (lane & 15);
    int koff = (lane >> 4) * 8;
    for (int kk = 0; kk < KTOT; kk += 32) {
        bf16x8 a[4], bb[4];
        #pragma unroll
        for (int mf = 0; mf < 4; mf++)
            a[mf] = ld8(A + (size_t)(mrow + mf * 16) * lda + kk + koff);
        #pragma unroll
        for (int nf = 0; nf < 4; nf++)
            bb[nf] = ld8(Bm + (size_t)(nrow + nf * 16) * ldb + kk + koff);
        #pragma unroll
        for (int mf = 0; mf < 4; mf++)
            #pragma unroll
            for (int nf = 0; nf < 4; nf++)
                acc[mf][nf] = __builtin_amdgcn_mfma_f32_16x16x32_bf16(
                    a[mf], bb[nf], acc[mf][nf], 0, 0, 0);
    }
}

// qk_t[b][p][o] = sum_c hnT[b][p][c] * wqkv[o][c] + qkv_b[o], o in [0,1024)
__global__ __launch_bounds__(256) void gemm_qk(const bf16* __restrict__ hnT,
                                               const bf16* __restrict__ wqkv,
                                               const float* __restrict__ qkv_b,
                                               bf16* __restrict__ qk_t) {
    int b = blockIdx.z;
    int wave = threadIdx.x >> 6, lane = threadIdx.x & 63;
    int m_base = blockIdx.x * 128 + (wave >> 1) * 64;  // p
    int n_base = blockIdx.y * 128 + (wave & 1) * 64;   // o
    const bf16* A = hnT + (size_t)b * 1024 * 512;
    f32x4 acc[4][4] = {};
    gemm_core<512>(A, wqkv, 512, 512, m_base, n_base, lane, acc);
    bf16* out = qk_t + (size_t)b * 1024 * 1024;
    int col0 = n_base + (lane & 15);
    int row0 = m_base + (lane >> 4) * 4;
    #pragma unroll
    for (int nf = 0; nf < 4; nf++) {
        float bias = qkv_b[col0 + nf * 16];
        #pragma unroll
        for (int mf = 0; mf < 4; mf++)
            #pragma unroll
            for (int r = 0; r < 4; r++)
                out[(size_t)(row0 + mf * 16 + r) * 1024 + col0 + nf * 16] =
                    (bf16)(acc[mf][nf][r] + bias);
    }
}

// vbuf[b][o][p] = sum_c wv[o][c] * hnT[b][p][c] + qkv_b[1024+o], o in [0,512)
__global__ __launch_bounds__(256) void gemm_v(const bf16* __restrict__ wv,
                                              const bf16* __restrict__ hnT,
                                              const float* __restrict__ qkv_b,
                                              bf16* __restrict__ vbuf) {
    int b = blockIdx.z;
    int wave = threadIdx.x >> 6, lane = threadIdx.x & 63;
    int m_base = blockIdx.x * 128 + (wave >> 1) * 64;  // o
    int n_base = blockIdx.y * 128 + (wave & 1) * 64;   // p
    const bf16* Bm = hnT + (size_t)b * 1024 * 512;
    f32x4 acc[4][4] = {};
    gemm_core<512>(wv, Bm, 512, 512, m_base, n_base, lane, acc);
    bf16* out = vbuf + (size_t)b * 512 * 1024;
    int col0 = n_base + (lane & 15);
    int row0 = m_base + (lane >> 4) * 4;
    #pragma unroll
    for (int mf = 0; mf < 4; mf++)
        #pragma unroll
        for (int r = 0; r < 4; r++) {
            float bias = qkv_b[1024 + row0 + mf * 16 + r];
            #pragma unroll
            for (int nf = 0; nf < 4; nf++)
                out[(size_t)(row0 + mf * 16 + r) * 1024 + col0 + nf * 16] =
                    (bf16)(acc[mf][nf][r] + bias);
        }
}

// out[b][o][i] = sum_c wproj[o][c] * attnT[b][i][c] + proj_b[o] + x[b][o][i]
__global__ __launch_bounds__(256) void gemm_proj(const bf16* __restrict__ wproj,
                                                 const bf16* __restrict__ attnT,
                                                 const float* __restrict__ proj_b,
                                                 const float* __restrict__ x,
                                                 float* __restrict__ out) {
    int b = blockIdx.z;
    int wave = threadIdx.x >> 6, lane = threadIdx.x & 63;
    int m_base = blockIdx.x * 128 + (wave >> 1) * 64;  // o
    int n_base = blockIdx.y * 128 + (wave & 1) * 64;   // i
    const bf16* Bm = attnT + (size_t)b * 1024 * 512;
    f32x4 acc[4][4] = {};
    gemm_core<512>(wproj, Bm, 512, 512, m_base, n_base, lane, acc);
    const float* xb = x + (size_t)b * 512 * 1024;
    float* ob = out + (size_t)b * 512 * 1024;
    int col0 = n_base + (lane & 15);
    int row0 = m_base + (lane >> 4) * 4;
    #pragma unroll
    for (int mf = 0; mf < 4; mf++)
        #pragma unroll
        for (int r = 0; r < 4; r++) {
            int row = row0 + mf * 16 + r;
            float bias = proj_b[row];
            #pragma unroll
            for (int nf = 0; nf < 4; nf++) {
                size_t idx = (size_t)row * 1024 + col0 + nf * 16;
                ob[idx] = acc[mf][nf][r] + bias + xb[idx];
            }
        }
}

// ---------------- flash attention ----------------
// Grid: 1024 blocks flat = [it 8][bh 128]; all 8 it-tiles of one (b,h) land on the
// same XCD (flat % 8 preserved under round-robin dispatch) -> K/V L2-resident.
// 4 waves/block, QBLK=32/wave. NO barriers (P_lds strictly per-wave).
// NO online max: logits are q.k/8 with group-normed inputs (|s| ~ O(3) << 88), so
// softmax = exp2(s*0.125*log2e) / sum, overflow-free in f32. This removes the
// max shfl-tree, corr exp, and oacc rescale from the serial chain; the row-sum
// reduction is deferred out of the j-loop (per-lane partials, one shfl tree at end).
__global__ __launch_bounds__(256, 2) void attn_kernel(const bf16* __restrict__ qk_t,
                                                      const bf16* __restrict__ vbuf,
                                                      bf16* __restrict__ attnT) {
    int flat = blockIdx.x;
    int it = flat >> 7;          // 0..7 (128-query tiles)
    int bh = flat & 127;
    int b = bh >> 3, h = bh & 7;
    int wave = threadIdx.x >> 6, lane = threadIdx.x & 63;
    int i0 = it * 128 + wave * 32;
    const bf16* qkb = qk_t + (size_t)b * 1024 * 1024;
    const bf16* vb = vbuf + ((size_t)b * 512 + h * 64) * 1024;
    int l15 = lane & 15;
    int koff = (lane >> 4) * 8;
    const float C = 0.18033688f;  // 0.125 * log2(e)

    // Q fragments: 2 row-tiles of 16 x K=64
    bf16x8 aq[2][2];
    #pragma unroll
    for (int mi = 0; mi < 2; mi++)
        #pragma unroll
        for (int kc = 0; kc < 2; kc++)
            aq[mi][kc] = ld8(qkb + (size_t)(i0 + mi * 16 + l15) * 1024 + h * 64 + kc * 32 + koff);

    f32x4 l_part[2] = {};
    f32x4 oacc[2][4] = {};

    __shared__ __align__(16) bf16 P_lds[4][32][72];  // per-wave, +8 pad

    for (int j0 = 0; j0 < 1024; j0 += 64) {
        // ---- K fragments for this tile ----
        bf16x8 kf[4][2];
        #pragma unroll
        for (int jf = 0; jf < 4; jf++)
            #pragma unroll
            for (int kc = 0; kc < 2; kc++)
                kf[jf][kc] = ld8(qkb + (size_t)(j0 + jf * 16 + l15) * 1024 +
                                 512 + h * 64 + kc * 32 + koff);
        // ---- V fragments issued early: in flight during QK + exp ----
        bf16x8 vf[4][2];
        #pragma unroll
        for (int cf = 0; cf < 4; cf++)
            #pragma unroll
            for (int ks = 0; ks < 2; ks++)
                vf[cf][ks] = ld8(vb + (size_t)(cf * 16 + l15) * 1024 + j0 + ks * 32 + koff);

        // ---- QK^T: 64 keys x 32 queries ----
        f32x4 s[2][4] = {};
        #pragma unroll
        for (int kc = 0; kc < 2; kc++)
            #pragma unroll
            for (int mi = 0; mi < 2; mi++)
                #pragma unroll
                for (int jf = 0; jf < 4; jf++)
                    s[mi][jf] = __builtin_amdgcn_mfma_f32_16x16x32_bf16(
                        aq[mi][kc], kf[jf][kc], s[mi][jf], 0, 0, 0);

        // ---- exp (no max, no cross-lane) + P -> LDS + partial row sums ----
        #pragma unroll
        for (int mi = 0; mi < 2; mi++)
            #pragma unroll
            for (int jf = 0; jf < 4; jf++)
                #pragma unroll
                for (int r = 0; r < 4; r++) {
                    float p = exp2f(s[mi][jf][r] * C);
                    l_part[mi][r] += p;
                    P_lds[wave][mi * 16 + (lane >> 4) * 4 + r][jf * 16 + l15] = (bf16)p;
                }

        // ---- PV: oacc[mi][cf] += P[mi] * V[cf]^T ----
        #pragma unroll
        for (int ks = 0; ks < 2; ks++) {
            bf16x8 pa[2];
            pa[0] = ld8(&P_lds[wave][l15][ks * 32 + koff]);
            pa[1] = ld8(&P_lds[wave][16 + l15][ks * 32 + koff]);
            #pragma unroll
            for (int cf = 0; cf < 4; cf++) {
                oacc[0][cf] = __builtin_amdgcn_mfma_f32_16x16x32_bf16(pa[0], vf[cf][ks], oacc[0][cf], 0, 0, 0);
                oacc[1][cf] = __builtin_amdgcn_mfma_f32_16x16x32_bf16(pa[1], vf[cf][ks], oacc[1][cf], 0, 0, 0);
            }
        }
    }

    // ---- deferred row-sum reduce (16-lane groups) + normalize + store ----
    #pragma unroll
    for (int mi = 0; mi < 2; mi++) {
        bf16* ob = attnT + ((size_t)b * 1024 + i0 + mi * 16 + (lane >> 4) * 4) * 512 +
                   h * 64 + l15;
        #pragma unroll
        for (int r = 0; r < 4; r++) {
            float lsum = l_part[mi][r];
            #pragma unroll
            for (int off = 1; off < 16; off <<= 1) lsum += __shfl_xor(lsum, off);
            float inv = 1.f / lsum;
            #pragma unroll
            for (int cf = 0; cf < 4; cf++)
                ob[(size_t)r * 512 + cf * 16] = (bf16)(oacc[mi][cf][r] * inv);
        }
    }
}

extern "C" void kernel_launch(void* const* d_in, const int* in_sizes, int n_in,
                              void* d_out, int out_size, void* d_ws, size_t ws_size,
                              hipStream_t stream) {
    (void)in_sizes; (void)n_in; (void)out_size; (void)ws_size;
    const float* x      = (const float*)d_in[0];
    const float* norm_w = (const float*)d_in[1];
    const float* norm_b = (const float*)d_in[2];
    const float* qkv_w  = (const float*)d_in[3];
    const float* qkv_b  = (const float*)d_in[4];
    const float* proj_w = (const float*)d_in[5];
    const float* proj_b = (const float*)d_in[6];
    float* out = (float*)d_out;

    // workspace layout (~86 MB)
    char* w = (char*)d_ws;
    bf16* wqkv  = (bf16*)w;                        // 1536*512
    bf16* wproj = wqkv + (size_t)1536 * 512;       // 512*512
    float2* stats = (float2*)(wproj + (size_t)512 * 512);  // 128
    bf16* hnT   = (bf16*)((char*)stats + 1024);    // [16][1024][512]
    bf16* qk_t  = hnT + (size_t)16 * 1024 * 512;   // [16][1024][1024]
    bf16* vbuf  = qk_t + (size_t)16 * 1024 * 1024; // [16][512][1024]
    bf16* attnT = vbuf + (size_t)16 * 512 * 1024;  // [16][1024][512]

    cvt_fp32_bf16<<<768, 256, 0, stream>>>(qkv_w, wqkv, 1536 * 512);
    cvt_fp32_bf16<<<256, 256, 0, stream>>>(proj_w, wproj, 512 * 512);
    gn_stats<<<128, 256, 0, stream>>>(x, stats);
    gn_apply_t<<<dim3(16, 8, 16), 256, 0, stream>>>(x, norm_w, norm_b, stats, hnT);
    gemm_qk<<<dim3(8, 8, 16), 256, 0, stream>>>(hnT, wqkv, qkv_b, qk_t);
    gemm_v<<<dim3(4, 8, 16), 256, 0, stream>>>(wqkv + (size_t)1024 * 512, hnT, qkv_b, vbuf);
    attn_kernel<<<1024, 256, 0, stream>>>(qk_t, vbuf, attnT);
    gemm_proj<<<dim3(4, 8, 16), 256, 0, stream>>>(wproj, attnT, proj_b, x, out);
}

// Round 4
// 248.182 us; speedup vs baseline: 1.7488x; 1.1966x over previous
//
#include <hip/hip_runtime.h>
#include <hip/hip_bf16.h>

// AttentionBlock: groupnorm -> qkv conv1x1 -> MHA (8 heads, hd=64) -> proj -> residual
// B=16, C=512, H=W=32 (HW=1024). All GEMM-shaped work in bf16 MFMA 16x16x32, fp32 accum.

typedef __bf16 bf16;
typedef __attribute__((ext_vector_type(8))) __bf16 bf16x8;
typedef __attribute__((ext_vector_type(4))) float f32x4;

#define SCALE_Q 0.18033688f  // 0.125 * log2(e), folded into q at gemm_qk epilogue

__device__ __forceinline__ bf16x8 ld8(const bf16* p) {
    return *reinterpret_cast<const bf16x8*>(p);
}

__device__ __forceinline__ void gl_lds16(const void* g, void* l) {
    __builtin_amdgcn_global_load_lds(
        (const __attribute__((address_space(1))) void*)g,
        (__attribute__((address_space(3))) void*)l, 16, 0, 0);
}

// ---------------- weight fp32 -> bf16 ----------------
__global__ __launch_bounds__(256) void cvt_fp32_bf16(const float* __restrict__ src,
                                                     bf16* __restrict__ dst, int n) {
    int i = (blockIdx.x * blockDim.x + threadIdx.x) * 4;
    int stride = gridDim.x * blockDim.x * 4;
    for (; i < n; i += stride) {
        float4 f = *reinterpret_cast<const float4*>(src + i);
        dst[i + 0] = (bf16)f.x;
        dst[i + 1] = (bf16)f.y;
        dst[i + 2] = (bf16)f.z;
        dst[i + 3] = (bf16)f.w;
    }
}

// ---------------- groupnorm stats: one block per (b,g) ----------------
__global__ __launch_bounds__(256) void gn_stats(const float* __restrict__ x,
                                                float2* __restrict__ stats) {
    int bg = blockIdx.x;
    const float* base = x + (size_t)bg * 65536;
    float s = 0.f, sq = 0.f;
    for (int i = threadIdx.x * 4; i < 65536; i += 256 * 4) {
        float4 f = *reinterpret_cast<const float4*>(base + i);
        s += f.x + f.y + f.z + f.w;
        sq += f.x * f.x + f.y * f.y + f.z * f.z + f.w * f.w;
    }
    #pragma unroll
    for (int off = 32; off > 0; off >>= 1) {
        s += __shfl_down(s, off);
        sq += __shfl_down(sq, off);
    }
    __shared__ float ls[4], lq[4];
    int wave = threadIdx.x >> 6, lane = threadIdx.x & 63;
    if (lane == 0) { ls[wave] = s; lq[wave] = sq; }
    __syncthreads();
    if (threadIdx.x == 0) {
        s = ls[0] + ls[1] + ls[2] + ls[3];
        sq = lq[0] + lq[1] + lq[2] + lq[3];
        float mean = s * (1.f / 65536.f);
        float var = sq * (1.f / 65536.f) - mean * mean;
        stats[bg] = make_float2(mean, rsqrtf(var + 1e-5f));
    }
}

// ---------------- groupnorm apply + transpose: hnT[b][p][c] bf16 ----------------
__global__ __launch_bounds__(256) void gn_apply_t(const float* __restrict__ x,
                                                  const float* __restrict__ gamma,
                                                  const float* __restrict__ beta,
                                                  const float2* __restrict__ stats,
                                                  bf16* __restrict__ hnT) {
    int b = blockIdx.z, ct = blockIdx.y, pt = blockIdx.x;
    __shared__ float tile[64][65];
    int t = threadIdx.x;
    const float* xb = x + ((size_t)b * 512 + ct * 64) * 1024 + pt * 64;
    #pragma unroll
    for (int r = 0; r < 16; r++) {
        int cl = r * 4 + (t >> 6);
        int pl = t & 63;
        tile[cl][pl] = xb[(size_t)cl * 1024 + pl];
    }
    __syncthreads();
    float2 mr = stats[b * 8 + ct];   // c-tile == group (both 64 wide)
    int cl = t & 63;
    float g = gamma[ct * 64 + cl], be = beta[ct * 64 + cl];
    bf16* ob = hnT + ((size_t)b * 1024 + pt * 64) * 512 + ct * 64;
    #pragma unroll
    for (int r = 0; r < 16; r++) {
        int pl = r * 4 + (t >> 6);
        float v = (tile[cl][pl] - mr.x) * mr.y * g + be;
        ob[(size_t)pl * 512 + cl] = (bf16)v;
    }
}

// ---------------- staged NT-GEMM core (m97 structure) ----------------
// 128x128 tile, BK=64, K=512 (8 k-steps), 4 waves (2x2 of 64x64).
// LDS: 2 bufs x (A 16KB + B 16KB) = 64KB. global_load_lds width=16, with
// pre-swizzled global source so LDS[r][chunk c] holds global chunk c^(r&7);
// ds_read_b128 applies the same XOR -> conflict-free minimum (8 lanes/span).
__device__ __forceinline__ void gemm_stage(const bf16* __restrict__ A,
                                           const bf16* __restrict__ B,
                                           char* smem, int buf,
                                           int m_blk, int n_blk, int k0,
                                           int wave, int lane) {
    char* Al = smem + buf * 32768;
    char* Bl = Al + 16384;
    #pragma unroll
    for (int i = 0; i < 4; i++) {
        int seg = i * 4 + wave;              // 16 segs of 1KB per 16KB tile
        int r = seg * 8 + (lane >> 3);       // tile row this lane fills
        int cg = (lane & 7) ^ (r & 7);       // pre-swizzled source chunk
        gl_lds16((const char*)(A + (size_t)(m_blk + r) * 512 + k0) + cg * 16,
                 Al + seg * 1024);
        gl_lds16((const char*)(B + (size_t)(n_blk + r) * 512 + k0) + cg * 16,
                 Bl + seg * 1024);
    }
}

__device__ __forceinline__ void gemm_compute(const char* smem, int buf,
                                             int wave, int lane,
                                             f32x4 (&acc)[4][4]) {
    const char* Al = smem + buf * 32768;
    const char* Bl = Al + 16384;
    int l15 = lane & 15, hi = lane >> 4;
    int mb = (wave >> 1) * 64, nb = (wave & 1) * 64;
    #pragma unroll
    for (int kc = 0; kc < 2; kc++) {
        int ck = kc * 4 + hi;                // 16B chunk of the 64-wide k-slab
        bf16x8 a[4], b[4];
        #pragma unroll
        for (int mf = 0; mf < 4; mf++) {
            int row = mb + mf * 16 + l15;
            a[mf] = *reinterpret_cast<const bf16x8*>(Al + row * 128 + (ck ^ (row & 7)) * 16);
        }
        #pragma unroll
        for (int nf = 0; nf < 4; nf++) {
            int row = nb + nf * 16 + l15;
            b[nf] = *reinterpret_cast<const bf16x8*>(Bl + row * 128 + (ck ^ (row & 7)) * 16);
        }
        #pragma unroll
        for (int mf = 0; mf < 4; mf++)
            #pragma unroll
            for (int nf = 0; nf < 4; nf++)
                acc[mf][nf] = __builtin_amdgcn_mfma_f32_16x16x32_bf16(
                    a[mf], b[nf], acc[mf][nf], 0, 0, 0);
    }
}

#define GEMM_LDS_LOOP(A_, B_)                                   \
    __shared__ char smem[65536];                                \
    f32x4 acc[4][4] = {};                                       \
    {                                                           \
        gemm_stage(A_, B_, smem, 0, m_blk, n_blk, 0, wave, lane); \
        __syncthreads();                                        \
        int buf = 0;                                            \
        for (int ks = 0; ks < 8; ks++) {                        \
            if (ks < 7)                                         \
                gemm_stage(A_, B_, smem, buf ^ 1, m_blk, n_blk, (ks + 1) * 64, wave, lane); \
            gemm_compute(smem, buf, wave, lane, acc);           \
            __syncthreads();                                    \
            buf ^= 1;                                           \
        }                                                       \
    }

// qk_t[b][p][o] = sum_c hnT[b][p][c]*wqkv[o][c] + qkv_b[o]; q cols (<512) scaled
__global__ __launch_bounds__(256, 2) void gemm_qk(const bf16* __restrict__ hnT,
                                                  const bf16* __restrict__ wqkv,
                                                  const float* __restrict__ qkv_b,
                                                  bf16* __restrict__ qk_t) {
    int b = blockIdx.z;
    int wave = threadIdx.x >> 6, lane = threadIdx.x & 63;
    int m_blk = blockIdx.x * 128;            // p
    int n_blk = blockIdx.y * 128;            // o
    const bf16* A = hnT + (size_t)b * 1024 * 512;
    GEMM_LDS_LOOP(A, wqkv)
    bf16* out = qk_t + (size_t)b * 1024 * 1024;
    int l15 = lane & 15;
    int col0 = n_blk + (wave & 1) * 64 + l15;
    int row0 = m_blk + (wave >> 1) * 64 + (lane >> 4) * 4;
    #pragma unroll
    for (int nf = 0; nf < 4; nf++) {
        int col = col0 + nf * 16;
        float bias = qkv_b[col];
        float scl = (col < 512) ? SCALE_Q : 1.0f;
        #pragma unroll
        for (int mf = 0; mf < 4; mf++)
            #pragma unroll
            for (int r = 0; r < 4; r++)
                out[(size_t)(row0 + mf * 16 + r) * 1024 + col] =
                    (bf16)((acc[mf][nf][r] + bias) * scl);
    }
}

// vbuf[b][o][p] = sum_c wv[o][c]*hnT[b][p][c] + qkv_b[1024+o]
__global__ __launch_bounds__(256, 2) void gemm_v(const bf16* __restrict__ wv,
                                                 const bf16* __restrict__ hnT,
                                                 const float* __restrict__ qkv_b,
                                                 bf16* __restrict__ vbuf) {
    int b = blockIdx.z;
    int wave = threadIdx.x >> 6, lane = threadIdx.x & 63;
    int m_blk = blockIdx.x * 128;            // o
    int n_blk = blockIdx.y * 128;            // p
    const bf16* Bm = hnT + (size_t)b * 1024 * 512;
    GEMM_LDS_LOOP(wv, Bm)
    bf16* out = vbuf + (size_t)b * 512 * 1024;
    int l15 = lane & 15;
    int col0 = n_blk + (wave & 1) * 64 + l15;
    int row0 = m_blk + (wave >> 1) * 64 + (lane >> 4) * 4;
    #pragma unroll
    for (int mf = 0; mf < 4; mf++)
        #pragma unroll
        for (int r = 0; r < 4; r++) {
            int row = row0 + mf * 16 + r;
            float bias = qkv_b[1024 + row];
            #pragma unroll
            for (int nf = 0; nf < 4; nf++)
                out[(size_t)row * 1024 + col0 + nf * 16] = (bf16)(acc[mf][nf][r] + bias);
        }
}

// out[b][o][i] = sum_c wproj[o][c]*attnT[b][i][c] + proj_b[o] + x[b][o][i]
__global__ __launch_bounds__(256, 2) void gemm_proj(const bf16* __restrict__ wproj,
                                                    const bf16* __restrict__ attnT,
                                                    const float* __restrict__ proj_b,
                                                    const float* __restrict__ x,
                                                    float* __restrict__ out) {
    int b = blockIdx.z;
    int wave = threadIdx.x >> 6, lane = threadIdx.x & 63;
    int m_blk = blockIdx.x * 128;            // o
    int n_blk = blockIdx.y * 128;            // i
    const bf16* Bm = attnT + (size_t)b * 1024 * 512;
    GEMM_LDS_LOOP(wproj, Bm)
    const float* xb = x + (size_t)b * 512 * 1024;
    float* ob = out + (size_t)b * 512 * 1024;
    int l15 = lane & 15;
    int col0 = n_blk + (wave & 1) * 64 + l15;
    int row0 = m_blk + (wave >> 1) * 64 + (lane >> 4) * 4;
    #pragma unroll
    for (int mf = 0; mf < 4; mf++)
        #pragma unroll
        for (int r = 0; r < 4; r++) {
            int row = row0 + mf * 16 + r;
            float bias = proj_b[row];
            #pragma unroll
            for (int nf = 0; nf < 4; nf++) {
                size_t idx = (size_t)row * 1024 + col0 + nf * 16;
                ob[idx] = acc[mf][nf][r] + bias + xb[idx];
            }
        }
}

// ---------------- flash attention ----------------
// Grid: 1024 blocks flat = [it 8][bh 128]; all 8 it-tiles of one (b,h) land on the
// same XCD (flat % 8 preserved under round-robin dispatch) -> K/V L2-resident.
// 4 waves/block, QBLK=32/wave. NO barriers (P_lds strictly per-wave).
// q is pre-scaled by 0.125*log2(e) in gemm_qk, so P = exp2f(s) directly.
__global__ __launch_bounds__(256, 2) void attn_kernel(const bf16* __restrict__ qk_t,
                                                      const bf16* __restrict__ vbuf,
                                                      bf16* __restrict__ attnT) {
    int flat = blockIdx.x;
    int it = flat >> 7;          // 0..7 (128-query tiles)
    int bh = flat & 127;
    int b = bh >> 3, h = bh & 7;
    int wave = threadIdx.x >> 6, lane = threadIdx.x & 63;
    int i0 = it * 128 + wave * 32;
    const bf16* qkb = qk_t + (size_t)b * 1024 * 1024;
    const bf16* vb = vbuf + ((size_t)b * 512 + h * 64) * 1024;
    int l15 = lane & 15;
    int koff = (lane >> 4) * 8;

    // Q fragments: 2 row-tiles of 16 x K=64
    bf16x8 aq[2][2];
    #pragma unroll
    for (int mi = 0; mi < 2; mi++)
        #pragma unroll
        for (int kc = 0; kc < 2; kc++)
            aq[mi][kc] = ld8(qkb + (size_t)(i0 + mi * 16 + l15) * 1024 + h * 64 + kc * 32 + koff);

    f32x4 l_part[2] = {};
    f32x4 oacc[2][4] = {};

    __shared__ __align__(16) bf16 P_lds[4][32][72];  // per-wave, +8 pad

    for (int j0 = 0; j0 < 1024; j0 += 64) {
        // ---- K fragments for this tile ----
        bf16x8 kf[4][2];
        #pragma unroll
        for (int jf = 0; jf < 4; jf++)
            #pragma unroll
            for (int kc = 0; kc < 2; kc++)
                kf[jf][kc] = ld8(qkb + (size_t)(j0 + jf * 16 + l15) * 1024 +
                                 512 + h * 64 + kc * 32 + koff);
        // ---- V fragments issued early: in flight during QK + exp ----
        bf16x8 vf[4][2];
        #pragma unroll
        for (int cf = 0; cf < 4; cf++)
            #pragma unroll
            for (int ks = 0; ks < 2; ks++)
                vf[cf][ks] = ld8(vb + (size_t)(cf * 16 + l15) * 1024 + j0 + ks * 32 + koff);

        // ---- QK^T: 64 keys x 32 queries ----
        f32x4 s[2][4] = {};
        #pragma unroll
        for (int kc = 0; kc < 2; kc++)
            #pragma unroll
            for (int mi = 0; mi < 2; mi++)
                #pragma unroll
                for (int jf = 0; jf < 4; jf++)
                    s[mi][jf] = __builtin_amdgcn_mfma_f32_16x16x32_bf16(
                        aq[mi][kc], kf[jf][kc], s[mi][jf], 0, 0, 0);

        // ---- exp (no max, no cross-lane) + P -> LDS + partial row sums ----
        #pragma unroll
        for (int mi = 0; mi < 2; mi++)
            #pragma unroll
            for (int jf = 0; jf < 4; jf++)
                #pragma unroll
                for (int r = 0; r < 4; r++) {
                    float p = exp2f(s[mi][jf][r]);
                    l_part[mi][r] += p;
                    P_lds[wave][mi * 16 + (lane >> 4) * 4 + r][jf * 16 + l15] = (bf16)p;
                }

        // ---- PV: oacc[mi][cf] += P[mi] * V[cf]^T ----
        #pragma unroll
        for (int ks = 0; ks < 2; ks++) {
            bf16x8 pa[2];
            pa[0] = ld8(&P_lds[wave][l15][ks * 32 + koff]);
            pa[1] = ld8(&P_lds[wave][16 + l15][ks * 32 + koff]);
            #pragma unroll
            for (int cf = 0; cf < 4; cf++) {
                oacc[0][cf] = __builtin_amdgcn_mfma_f32_16x16x32_bf16(pa[0], vf[cf][ks], oacc[0][cf], 0, 0, 0);
                oacc[1][cf] = __builtin_amdgcn_mfma_f32_16x16x32_bf16(pa[1], vf[cf][ks], oacc[1][cf], 0, 0, 0);
            }
        }
    }

    // ---- deferred row-sum reduce (16-lane groups) + normalize + store ----
    #pragma unroll
    for (int mi = 0; mi < 2; mi++) {
        bf16* ob = attnT + ((size_t)b * 1024 + i0 + mi * 16 + (lane >> 4) * 4) * 512 +
                   h * 64 + l15;
        #pragma unroll
        for (int r = 0; r < 4; r++) {
            float lsum = l_part[mi][r];
            #pragma unroll
            for (int off = 1; off < 16; off <<= 1) lsum += __shfl_xor(lsum, off);
            float inv = 1.f / lsum;
            #pragma unroll
            for (int cf = 0; cf < 4; cf++)
                ob[(size_t)r * 512 + cf * 16] = (bf16)(oacc[mi][cf][r] * inv);
        }
    }
}

extern "C" void kernel_launch(void* const* d_in, const int* in_sizes, int n_in,
                              void* d_out, int out_size, void* d_ws, size_t ws_size,
                              hipStream_t stream) {
    (void)in_sizes; (void)n_in; (void)out_size; (void)ws_size;
    const float* x      = (const float*)d_in[0];
    const float* norm_w = (const float*)d_in[1];
    const float* norm_b = (const float*)d_in[2];
    const float* qkv_w  = (const float*)d_in[3];
    const float* qkv_b  = (const float*)d_in[4];
    const float* proj_w = (const float*)d_in[5];
    const float* proj_b = (const float*)d_in[6];
    float* out = (float*)d_out;

    // workspace layout (~86 MB)
    char* w = (char*)d_ws;
    bf16* wqkv  = (bf16*)w;                        // 1536*512
    bf16* wproj = wqkv + (size_t)1536 * 512;       // 512*512
    float2* stats = (float2*)(wproj + (size_t)512 * 512);  // 128
    bf16* hnT   = (bf16*)((char*)stats + 1024);    // [16][1024][512]
    bf16* qk_t  = hnT + (size_t)16 * 1024 * 512;   // [16][1024][1024]
    bf16* vbuf  = qk_t + (size_t)16 * 1024 * 1024; // [16][512][1024]
    bf16* attnT = vbuf + (size_t)16 * 512 * 1024;  // [16][1024][512]

    cvt_fp32_bf16<<<768, 256, 0, stream>>>(qkv_w, wqkv, 1536 * 512);
    cvt_fp32_bf16<<<256, 256, 0, stream>>>(proj_w, wproj, 512 * 512);
    gn_stats<<<128, 256, 0, stream>>>(x, stats);
    gn_apply_t<<<dim3(16, 8, 16), 256, 0, stream>>>(x, norm_w, norm_b, stats, hnT);
    gemm_qk<<<dim3(8, 8, 16), 256, 0, stream>>>(hnT, wqkv, qkv_b, qk_t);
    gemm_v<<<dim3(4, 8, 16), 256, 0, stream>>>(wqkv + (size_t)1024 * 512, hnT, qkv_b, vbuf);
    attn_kernel<<<1024, 256, 0, stream>>>(qk_t, vbuf, attnT);
    gemm_proj<<<dim3(4, 8, 16), 256, 0, stream>>>(wproj, attnT, proj_b, x, out);
}

// Round 5
// 218.166 us; speedup vs baseline: 1.9894x; 1.1376x over previous
//
#include <hip/hip_runtime.h>
#include <hip/hip_bf16.h>

// AttentionBlock: groupnorm -> qkv conv1x1 -> MHA (8 heads, hd=64) -> proj -> residual
// B=16, C=512, H=W=32 (HW=1024). All GEMM-shaped work in bf16 MFMA, fp32 accum.

typedef __bf16 bf16;
typedef __attribute__((ext_vector_type(8))) __bf16 bf16x8;
typedef __attribute__((ext_vector_type(4))) float f32x4;
typedef __attribute__((ext_vector_type(16))) float f32x16;
typedef __attribute__((ext_vector_type(4))) unsigned int u32x4;

#define SCALE_Q 0.18033688f  // 0.125 * log2(e), folded into q at gemm_qk epilogue

__device__ __forceinline__ bf16x8 ld8(const bf16* p) {
    return *reinterpret_cast<const bf16x8*>(p);
}

__device__ __forceinline__ void gl_lds16(const void* g, void* l) {
    __builtin_amdgcn_global_load_lds(
        (const __attribute__((address_space(1))) void*)g,
        (__attribute__((address_space(3))) void*)l, 16, 0, 0);
}

// ---------------- weight fp32 -> bf16 ----------------
__global__ __launch_bounds__(256) void cvt_fp32_bf16(const float* __restrict__ src,
                                                     bf16* __restrict__ dst, int n) {
    int i = (blockIdx.x * blockDim.x + threadIdx.x) * 4;
    int stride = gridDim.x * blockDim.x * 4;
    for (; i < n; i += stride) {
        float4 f = *reinterpret_cast<const float4*>(src + i);
        dst[i + 0] = (bf16)f.x;
        dst[i + 1] = (bf16)f.y;
        dst[i + 2] = (bf16)f.z;
        dst[i + 3] = (bf16)f.w;
    }
}

// ---------------- groupnorm stats: one block per (b,g) ----------------
__global__ __launch_bounds__(256) void gn_stats(const float* __restrict__ x,
                                                float2* __restrict__ stats) {
    int bg = blockIdx.x;
    const float* base = x + (size_t)bg * 65536;
    float s = 0.f, sq = 0.f;
    for (int i = threadIdx.x * 4; i < 65536; i += 256 * 4) {
        float4 f = *reinterpret_cast<const float4*>(base + i);
        s += f.x + f.y + f.z + f.w;
        sq += f.x * f.x + f.y * f.y + f.z * f.z + f.w * f.w;
    }
    #pragma unroll
    for (int off = 32; off > 0; off >>= 1) {
        s += __shfl_down(s, off);
        sq += __shfl_down(sq, off);
    }
    __shared__ float ls[4], lq[4];
    int wave = threadIdx.x >> 6, lane = threadIdx.x & 63;
    if (lane == 0) { ls[wave] = s; lq[wave] = sq; }
    __syncthreads();
    if (threadIdx.x == 0) {
        s = ls[0] + ls[1] + ls[2] + ls[3];
        sq = lq[0] + lq[1] + lq[2] + lq[3];
        float mean = s * (1.f / 65536.f);
        float var = sq * (1.f / 65536.f) - mean * mean;
        stats[bg] = make_float2(mean, rsqrtf(var + 1e-5f));
    }
}

// ---------------- groupnorm apply + transpose: hnT[b][p][c] bf16 ----------------
__global__ __launch_bounds__(256) void gn_apply_t(const float* __restrict__ x,
                                                  const float* __restrict__ gamma,
                                                  const float* __restrict__ beta,
                                                  const float2* __restrict__ stats,
                                                  bf16* __restrict__ hnT) {
    int b = blockIdx.z, ct = blockIdx.y, pt = blockIdx.x;
    __shared__ float tile[64][65];
    int t = threadIdx.x;
    const float* xb = x + ((size_t)b * 512 + ct * 64) * 1024 + pt * 64;
    #pragma unroll
    for (int r = 0; r < 16; r++) {
        int cl = r * 4 + (t >> 6);
        int pl = t & 63;
        tile[cl][pl] = xb[(size_t)cl * 1024 + pl];
    }
    __syncthreads();
    float2 mr = stats[b * 8 + ct];   // c-tile == group (both 64 wide)
    int cl = t & 63;
    float g = gamma[ct * 64 + cl], be = beta[ct * 64 + cl];
    bf16* ob = hnT + ((size_t)b * 1024 + pt * 64) * 512 + ct * 64;
    #pragma unroll
    for (int r = 0; r < 16; r++) {
        int pl = r * 4 + (t >> 6);
        float v = (tile[cl][pl] - mr.x) * mr.y * g + be;
        ob[(size_t)pl * 512 + cl] = (bf16)v;
    }
}

// ---------------- staged NT-GEMM core (m97 structure) ----------------
// 128x128 tile, BK=64, K=512 (8 k-steps), 4 waves (2x2 of 64x64).
// LDS: 2 bufs x (A 16KB + B 16KB) = 64KB. global_load_lds width=16, with
// pre-swizzled global source so LDS[r][chunk c] holds global chunk c^(r&7);
// ds_read_b128 applies the same XOR -> conflict-free minimum (8 lanes/span).
__device__ __forceinline__ void gemm_stage(const bf16* __restrict__ A,
                                           const bf16* __restrict__ B,
                                           char* smem, int buf,
                                           int m_blk, int n_blk, int k0,
                                           int wave, int lane) {
    char* Al = smem + buf * 32768;
    char* Bl = Al + 16384;
    #pragma unroll
    for (int i = 0; i < 4; i++) {
        int seg = i * 4 + wave;              // 16 segs of 1KB per 16KB tile
        int r = seg * 8 + (lane >> 3);       // tile row this lane fills
        int cg = (lane & 7) ^ (r & 7);       // pre-swizzled source chunk
        gl_lds16((const char*)(A + (size_t)(m_blk + r) * 512 + k0) + cg * 16,
                 Al + seg * 1024);
        gl_lds16((const char*)(B + (size_t)(n_blk + r) * 512 + k0) + cg * 16,
                 Bl + seg * 1024);
    }
}

__device__ __forceinline__ void gemm_compute(const char* smem, int buf,
                                             int wave, int lane,
                                             f32x4 (&acc)[4][4]) {
    const char* Al = smem + buf * 32768;
    const char* Bl = Al + 16384;
    int l15 = lane & 15, hi = lane >> 4;
    int mb = (wave >> 1) * 64, nb = (wave & 1) * 64;
    #pragma unroll
    for (int kc = 0; kc < 2; kc++) {
        int ck = kc * 4 + hi;                // 16B chunk of the 64-wide k-slab
        bf16x8 a[4], b[4];
        #pragma unroll
        for (int mf = 0; mf < 4; mf++) {
            int row = mb + mf * 16 + l15;
            a[mf] = *reinterpret_cast<const bf16x8*>(Al + row * 128 + (ck ^ (row & 7)) * 16);
        }
        #pragma unroll
        for (int nf = 0; nf < 4; nf++) {
            int row = nb + nf * 16 + l15;
            b[nf] = *reinterpret_cast<const bf16x8*>(Bl + row * 128 + (ck ^ (row & 7)) * 16);
        }
        #pragma unroll
        for (int mf = 0; mf < 4; mf++)
            #pragma unroll
            for (int nf = 0; nf < 4; nf++)
                acc[mf][nf] = __builtin_amdgcn_mfma_f32_16x16x32_bf16(
                    a[mf], b[nf], acc[mf][nf], 0, 0, 0);
    }
}

#define GEMM_LDS_LOOP(A_, B_)                                   \
    __shared__ char smem[65536];                                \
    f32x4 acc[4][4] = {};                                       \
    {                                                           \
        gemm_stage(A_, B_, smem, 0, m_blk, n_blk, 0, wave, lane); \
        __syncthreads();                                        \
        int buf = 0;                                            \
        for (int ks = 0; ks < 8; ks++) {                        \
            if (ks < 7)                                         \
                gemm_stage(A_, B_, smem, buf ^ 1, m_blk, n_blk, (ks + 1) * 64, wave, lane); \
            gemm_compute(smem, buf, wave, lane, acc);           \
            __syncthreads();                                    \
            buf ^= 1;                                           \
        }                                                       \
    }

// qk_t[b][p][o] = sum_c hnT[b][p][c]*wqkv[o][c] + qkv_b[o]; q cols (<512) scaled
__global__ __launch_bounds__(256, 2) void gemm_qk(const bf16* __restrict__ hnT,
                                                  const bf16* __restrict__ wqkv,
                                                  const float* __restrict__ qkv_b,
                                                  bf16* __restrict__ qk_t) {
    int b = blockIdx.z;
    int wave = threadIdx.x >> 6, lane = threadIdx.x & 63;
    int m_blk = blockIdx.x * 128;            // p
    int n_blk = blockIdx.y * 128;            // o
    const bf16* A = hnT + (size_t)b * 1024 * 512;
    GEMM_LDS_LOOP(A, wqkv)
    bf16* out = qk_t + (size_t)b * 1024 * 1024;
    int l15 = lane & 15;
    int col0 = n_blk + (wave & 1) * 64 + l15;
    int row0 = m_blk + (wave >> 1) * 64 + (lane >> 4) * 4;
    #pragma unroll
    for (int nf = 0; nf < 4; nf++) {
        int col = col0 + nf * 16;
        float bias = qkv_b[col];
        float scl = (col < 512) ? SCALE_Q : 1.0f;
        #pragma unroll
        for (int mf = 0; mf < 4; mf++)
            #pragma unroll
            for (int r = 0; r < 4; r++)
                out[(size_t)(row0 + mf * 16 + r) * 1024 + col] =
                    (bf16)((acc[mf][nf][r] + bias) * scl);
    }
}

// vbuf[b][o][p] = sum_c wv[o][c]*hnT[b][p][c] + qkv_b[1024+o]
__global__ __launch_bounds__(256, 2) void gemm_v(const bf16* __restrict__ wv,
                                                 const bf16* __restrict__ hnT,
                                                 const float* __restrict__ qkv_b,
                                                 bf16* __restrict__ vbuf) {
    int b = blockIdx.z;
    int wave = threadIdx.x >> 6, lane = threadIdx.x & 63;
    int m_blk = blockIdx.x * 128;            // o
    int n_blk = blockIdx.y * 128;            // p
    const bf16* Bm = hnT + (size_t)b * 1024 * 512;
    GEMM_LDS_LOOP(wv, Bm)
    bf16* out = vbuf + (size_t)b * 512 * 1024;
    int l15 = lane & 15;
    int col0 = n_blk + (wave & 1) * 64 + l15;
    int row0 = m_blk + (wave >> 1) * 64 + (lane >> 4) * 4;
    #pragma unroll
    for (int mf = 0; mf < 4; mf++)
        #pragma unroll
        for (int r = 0; r < 4; r++) {
            int row = row0 + mf * 16 + r;
            float bias = qkv_b[1024 + row];
            #pragma unroll
            for (int nf = 0; nf < 4; nf++)
                out[(size_t)row * 1024 + col0 + nf * 16] = (bf16)(acc[mf][nf][r] + bias);
        }
}

// out[b][o][i] = sum_c wproj[o][c]*attnT[b][i][c] + proj_b[o] + x[b][o][i]
__global__ __launch_bounds__(256, 2) void gemm_proj(const bf16* __restrict__ wproj,
                                                    const bf16* __restrict__ attnT,
                                                    const float* __restrict__ proj_b,
                                                    const float* __restrict__ x,
                                                    float* __restrict__ out) {
    int b = blockIdx.z;
    int wave = threadIdx.x >> 6, lane = threadIdx.x & 63;
    int m_blk = blockIdx.x * 128;            // o
    int n_blk = blockIdx.y * 128;            // i
    const bf16* Bm = attnT + (size_t)b * 1024 * 512;
    GEMM_LDS_LOOP(wproj, Bm)
    const float* xb = x + (size_t)b * 512 * 1024;
    float* ob = out + (size_t)b * 512 * 1024;
    int l15 = lane & 15;
    int col0 = n_blk + (wave & 1) * 64 + l15;
    int row0 = m_blk + (wave >> 1) * 64 + (lane >> 4) * 4;
    #pragma unroll
    for (int mf = 0; mf < 4; mf++)
        #pragma unroll
        for (int r = 0; r < 4; r++) {
            int row = row0 + mf * 16 + r;
            float bias = proj_b[row];
            #pragma unroll
            for (int nf = 0; nf < 4; nf++) {
                size_t idx = (size_t)row * 1024 + col0 + nf * 16;
                ob[idx] = acc[mf][nf][r] + bias + xb[idx];
            }
        }
}

// ---------------- flash attention, 32x32 MFMA, in-register P path ----------------
// Grid: 1024 blocks flat = [it 8][bh 128]; XCD-bijective (flat%8 = bh%8) -> K/V
// L2-resident per XCD. 4 waves/block, 32 queries/wave. ZERO LDS, ZERO barriers.
//
// Swapped QK^T: s[jb] = mfma_32x32x16(A=K-rows, B=Q-rows) -> D[j][q]:
//   col = lane&31 = q, row j = (reg&3) + 8*(reg>>2) + 4*(lane>>5)   [m74/m101]
// so each lane holds P values for its own query; softmax needs no cross-lane ops.
// P -> PV A-fragment in-register: PV A-frag (rows=q, k=j) needs lane (hi,q) to
// hold j = 16ks+8hi+e, e=0..7. Rows 8m..8m+3 live in lo-half regs 4m..4m+3,
// rows 8m+4..8m+7 in hi-half regs 4m..4m+3 (m = 2*(ks&1)+hi). cvt_pk packs reg
// pairs; permlane32_swap(pk[2t], pk[2t+1]) returns (lo-sourced, hi-sourced)
// words = A-frag words. 16 cvt_pk + 8 permlane per iter replace the LDS round-trip.
__global__ __launch_bounds__(256, 3) void attn_kernel(const bf16* __restrict__ qk_t,
                                                      const bf16* __restrict__ vbuf,
                                                      bf16* __restrict__ attnT) {
    int flat = blockIdx.x;
    int it = flat >> 7;          // 0..7 (128-query tiles)
    int bh = flat & 127;
    int b = bh >> 3, h = bh & 7;
    int wave = threadIdx.x >> 6, lane = threadIdx.x & 63;
    int l31 = lane & 31, hi = lane >> 5;
    int i0 = it * 128 + wave * 32;
    const bf16* qkb = qk_t + (size_t)b * 1024 * 1024;
    const bf16* vb = vbuf + ((size_t)b * 512 + h * 64) * 1024;

    // Q as B-operand: col=q=l31, k = 16kc + 8hi + e
    bf16x8 bq[4];
    #pragma unroll
    for (int kc = 0; kc < 4; kc++)
        bq[kc] = ld8(qkb + (size_t)(i0 + l31) * 1024 + h * 64 + kc * 16 + hi * 8);

    f32x16 oacc[2] = {};
    float l_part = 0.f;

    for (int j0 = 0; j0 < 1024; j0 += 64) {
        // K as A-operand: row j = j0+32jb+l31, k = 16kc + 8hi + e
        bf16x8 kf[2][4];
        #pragma unroll
        for (int jb = 0; jb < 2; jb++)
            #pragma unroll
            for (int kc = 0; kc < 4; kc++)
                kf[jb][kc] = ld8(qkb + (size_t)(j0 + jb * 32 + l31) * 1024 +
                                 512 + h * 64 + kc * 16 + hi * 8);
        // V as B-operand for PV (issued early, in flight through QK+exp):
        // row d = 32df+l31, k = j = j0 + 16ks + 8hi + e
        bf16x8 vf[2][4];
        #pragma unroll
        for (int df = 0; df < 2; df++)
            #pragma unroll
            for (int ks = 0; ks < 4; ks++)
                vf[df][ks] = ld8(vb + (size_t)(df * 32 + l31) * 1024 + j0 + ks * 16 + hi * 8);

        // ---- QK^T (swapped): s[jb] = K[jb-tile] . Q^T ----
        f32x16 s[2] = {};
        #pragma unroll
        for (int kc = 0; kc < 4; kc++) {
            s[0] = __builtin_amdgcn_mfma_f32_32x32x16_bf16(kf[0][kc], bq[kc], s[0], 0, 0, 0);
            s[1] = __builtin_amdgcn_mfma_f32_32x32x16_bf16(kf[1][kc], bq[kc], s[1], 0, 0, 0);
        }

        // ---- exp2 (scale pre-folded into q) + pack to bf16 pairs ----
        unsigned int pk0[2][4], pk1[2][4];
        #pragma unroll
        for (int jb = 0; jb < 2; jb++)
            #pragma unroll
            for (int m = 0; m < 4; m++) {
                float e0 = exp2f(s[jb][m * 4 + 0]);
                float e1 = exp2f(s[jb][m * 4 + 1]);
                float e2 = exp2f(s[jb][m * 4 + 2]);
                float e3 = exp2f(s[jb][m * 4 + 3]);
                l_part += (e0 + e1) + (e2 + e3);
                asm("v_cvt_pk_bf16_f32 %0, %1, %2" : "=v"(pk0[jb][m]) : "v"(e0), "v"(e1));
                asm("v_cvt_pk_bf16_f32 %0, %1, %2" : "=v"(pk1[jb][m]) : "v"(e2), "v"(e3));
            }

        // ---- permlane32_swap: build PV A-frags (4 x bf16x8) in-register ----
        bf16x8 af[4];
        #pragma unroll
        for (int jb = 0; jb < 2; jb++)
            #pragma unroll
            for (int t = 0; t < 2; t++) {
                unsigned int a0 = pk0[jb][t * 2], b0 = pk0[jb][t * 2 + 1];
                unsigned int a1 = pk1[jb][t * 2], b1 = pk1[jb][t * 2 + 1];
                asm("v_permlane32_swap_b32 %0, %1" : "+v"(a0), "+v"(b0));
                asm("v_permlane32_swap_b32 %0, %1" : "+v"(a1), "+v"(b1));
                u32x4 w = {a0, a1, b0, b1};   // e01, e23, e45, e67
                af[jb * 2 + t] = __builtin_bit_cast(bf16x8, w);
            }

        // ---- PV: oacc[df] += P . V^T ----
        #pragma unroll
        for (int ks = 0; ks < 4; ks++) {
            oacc[0] = __builtin_amdgcn_mfma_f32_32x32x16_bf16(af[ks], vf[0][ks], oacc[0], 0, 0, 0);
            oacc[1] = __builtin_amdgcn_mfma_f32_32x32x16_bf16(af[ks], vf[1][ks], oacc[1], 0, 0, 0);
        }
    }

    // ---- softmax denominator: per-lane partial covers this lane's j-rows;
    // lane (0,q) + lane (1,q) together cover all j for query q.
    float lsum = l_part + __shfl_xor(l_part, 32);
    float inv = 1.f / lsum;

    // ---- store O^T: lane holds O[q=(reg&3)+8(reg>>2)+4hi][d=32df+l31] ----
    bf16* ob = attnT + ((size_t)b * 1024 + i0) * 512 + h * 64 + l31;
    #pragma unroll
    for (int reg = 0; reg < 16; reg++) {
        int qrow = (reg & 3) + 8 * (reg >> 2) + 4 * hi;
        float iv = __shfl(inv, qrow);   // pulls from lo-half lane qrow
        ob[(size_t)qrow * 512]      = (bf16)(oacc[0][reg] * iv);
        ob[(size_t)qrow * 512 + 32] = (bf16)(oacc[1][reg] * iv);
    }
}

extern "C" void kernel_launch(void* const* d_in, const int* in_sizes, int n_in,
                              void* d_out, int out_size, void* d_ws, size_t ws_size,
                              hipStream_t stream) {
    (void)in_sizes; (void)n_in; (void)out_size; (void)ws_size;
    const float* x      = (const float*)d_in[0];
    const float* norm_w = (const float*)d_in[1];
    const float* norm_b = (const float*)d_in[2];
    const float* qkv_w  = (const float*)d_in[3];
    const float* qkv_b  = (const float*)d_in[4];
    const float* proj_w = (const float*)d_in[5];
    const float* proj_b = (const float*)d_in[6];
    float* out = (float*)d_out;

    // workspace layout (~86 MB)
    char* w = (char*)d_ws;
    bf16* wqkv  = (bf16*)w;                        // 1536*512
    bf16* wproj = wqkv + (size_t)1536 * 512;       // 512*512
    float2* stats = (float2*)(wproj + (size_t)512 * 512);  // 128
    bf16* hnT   = (bf16*)((char*)stats + 1024);    // [16][1024][512]
    bf16* qk_t  = hnT + (size_t)16 * 1024 * 512;   // [16][1024][1024]
    bf16* vbuf  = qk_t + (size_t)16 * 1024 * 1024; // [16][512][1024]
    bf16* attnT = vbuf + (size_t)16 * 512 * 1024;  // [16][1024][512]

    cvt_fp32_bf16<<<768, 256, 0, stream>>>(qkv_w, wqkv, 1536 * 512);
    cvt_fp32_bf16<<<256, 256, 0, stream>>>(proj_w, wproj, 512 * 512);
    gn_stats<<<128, 256, 0, stream>>>(x, stats);
    gn_apply_t<<<dim3(16, 8, 16), 256, 0, stream>>>(x, norm_w, norm_b, stats, hnT);
    gemm_qk<<<dim3(8, 8, 16), 256, 0, stream>>>(hnT, wqkv, qkv_b, qk_t);
    gemm_v<<<dim3(4, 8, 16), 256, 0, stream>>>(wqkv + (size_t)1024 * 512, hnT, qkv_b, vbuf);
    attn_kernel<<<1024, 256, 0, stream>>>(qk_t, vbuf, attnT);
    gemm_proj<<<dim3(4, 8, 16), 256, 0, stream>>>(wproj, attnT, proj_b, x, out);
}

// Round 6
// 147.847 us; speedup vs baseline: 2.9356x; 1.4756x over previous
//
#include <hip/hip_runtime.h>
#include <hip/hip_bf16.h>

// AttentionBlock: groupnorm -> qkv conv1x1 -> MHA (8 heads, hd=64) -> proj -> residual
// B=16, C=512, H=W=32 (HW=1024). All GEMM-shaped work in bf16 MFMA, fp32 accum.

typedef __bf16 bf16;
typedef __attribute__((ext_vector_type(8))) __bf16 bf16x8;
typedef __attribute__((ext_vector_type(4))) float f32x4;
typedef __attribute__((ext_vector_type(16))) float f32x16;
typedef __attribute__((ext_vector_type(4))) unsigned int u32x4;

#define SCALE_Q 0.18033688f  // 0.125 * log2(e), folded into q at gemm_qk epilogue

__device__ __forceinline__ bf16x8 ld8(const bf16* p) {
    return *reinterpret_cast<const bf16x8*>(p);
}

__device__ __forceinline__ void gl_lds16(const void* g, void* l) {
    __builtin_amdgcn_global_load_lds(
        (const __attribute__((address_space(1))) void*)g,
        (__attribute__((address_space(3))) void*)l, 16, 0, 0);
}

// ---------------- weight fp32 -> bf16 ----------------
__global__ __launch_bounds__(256) void cvt_fp32_bf16(const float* __restrict__ src,
                                                     bf16* __restrict__ dst, int n) {
    int i = (blockIdx.x * blockDim.x + threadIdx.x) * 4;
    int stride = gridDim.x * blockDim.x * 4;
    for (; i < n; i += stride) {
        float4 f = *reinterpret_cast<const float4*>(src + i);
        dst[i + 0] = (bf16)f.x;
        dst[i + 1] = (bf16)f.y;
        dst[i + 2] = (bf16)f.z;
        dst[i + 3] = (bf16)f.w;
    }
}

// ---------------- groupnorm stats: one block per (b,g) ----------------
__global__ __launch_bounds__(256) void gn_stats(const float* __restrict__ x,
                                                float2* __restrict__ stats) {
    int bg = blockIdx.x;
    const float* base = x + (size_t)bg * 65536;
    float s = 0.f, sq = 0.f;
    for (int i = threadIdx.x * 4; i < 65536; i += 256 * 4) {
        float4 f = *reinterpret_cast<const float4*>(base + i);
        s += f.x + f.y + f.z + f.w;
        sq += f.x * f.x + f.y * f.y + f.z * f.z + f.w * f.w;
    }
    #pragma unroll
    for (int off = 32; off > 0; off >>= 1) {
        s += __shfl_down(s, off);
        sq += __shfl_down(sq, off);
    }
    __shared__ float ls[4], lq[4];
    int wave = threadIdx.x >> 6, lane = threadIdx.x & 63;
    if (lane == 0) { ls[wave] = s; lq[wave] = sq; }
    __syncthreads();
    if (threadIdx.x == 0) {
        s = ls[0] + ls[1] + ls[2] + ls[3];
        sq = lq[0] + lq[1] + lq[2] + lq[3];
        float mean = s * (1.f / 65536.f);
        float var = sq * (1.f / 65536.f) - mean * mean;
        stats[bg] = make_float2(mean, rsqrtf(var + 1e-5f));
    }
}

// ---------------- groupnorm apply + transpose: hnT[b][p][c] bf16 ----------------
__global__ __launch_bounds__(256) void gn_apply_t(const float* __restrict__ x,
                                                  const float* __restrict__ gamma,
                                                  const float* __restrict__ beta,
                                                  const float2* __restrict__ stats,
                                                  bf16* __restrict__ hnT) {
    int b = blockIdx.z, ct = blockIdx.y, pt = blockIdx.x;
    __shared__ float tile[64][65];
    int t = threadIdx.x;
    const float* xb = x + ((size_t)b * 512 + ct * 64) * 1024 + pt * 64;
    #pragma unroll
    for (int r = 0; r < 16; r++) {
        int cl = r * 4 + (t >> 6);
        int pl = t & 63;
        tile[cl][pl] = xb[(size_t)cl * 1024 + pl];
    }
    __syncthreads();
    float2 mr = stats[b * 8 + ct];   // c-tile == group (both 64 wide)
    int cl = t & 63;
    float g = gamma[ct * 64 + cl], be = beta[ct * 64 + cl];
    bf16* ob = hnT + ((size_t)b * 1024 + pt * 64) * 512 + ct * 64;
    #pragma unroll
    for (int r = 0; r < 16; r++) {
        int pl = r * 4 + (t >> 6);
        float v = (tile[cl][pl] - mr.x) * mr.y * g + be;
        ob[(size_t)pl * 512 + cl] = (bf16)v;
    }
}

// ---------------- staged NT-GEMM core (m97 structure) ----------------
// 128x128 tile, BK=64, K=512 (8 k-steps), 4 waves (2x2 of 64x64).
// LDS: 2 bufs x (A 16KB + B 16KB) = 64KB. global_load_lds width=16, with
// pre-swizzled global source so LDS[r][chunk c] holds global chunk c^(r&7);
// ds_read_b128 applies the same XOR -> conflict-free minimum (8 lanes/span).
__device__ __forceinline__ void gemm_stage(const bf16* __restrict__ A,
                                           const bf16* __restrict__ B,
                                           char* smem, int buf,
                                           int m_blk, int n_blk, int k0,
                                           int wave, int lane) {
    char* Al = smem + buf * 32768;
    char* Bl = Al + 16384;
    #pragma unroll
    for (int i = 0; i < 4; i++) {
        int seg = i * 4 + wave;              // 16 segs of 1KB per 16KB tile
        int r = seg * 8 + (lane >> 3);       // tile row this lane fills
        int cg = (lane & 7) ^ (r & 7);       // pre-swizzled source chunk
        gl_lds16((const char*)(A + (size_t)(m_blk + r) * 512 + k0) + cg * 16,
                 Al + seg * 1024);
        gl_lds16((const char*)(B + (size_t)(n_blk + r) * 512 + k0) + cg * 16,
                 Bl + seg * 1024);
    }
}

__device__ __forceinline__ void gemm_compute(const char* smem, int buf,
                                             int wave, int lane,
                                             f32x4 (&acc)[4][4]) {
    const char* Al = smem + buf * 32768;
    const char* Bl = Al + 16384;
    int l15 = lane & 15, hi = lane >> 4;
    int mb = (wave >> 1) * 64, nb = (wave & 1) * 64;
    #pragma unroll
    for (int kc = 0; kc < 2; kc++) {
        int ck = kc * 4 + hi;                // 16B chunk of the 64-wide k-slab
        bf16x8 a[4], b[4];
        #pragma unroll
        for (int mf = 0; mf < 4; mf++) {
            int row = mb + mf * 16 + l15;
            a[mf] = *reinterpret_cast<const bf16x8*>(Al + row * 128 + (ck ^ (row & 7)) * 16);
        }
        #pragma unroll
        for (int nf = 0; nf < 4; nf++) {
            int row = nb + nf * 16 + l15;
            b[nf] = *reinterpret_cast<const bf16x8*>(Bl + row * 128 + (ck ^ (row & 7)) * 16);
        }
        #pragma unroll
        for (int mf = 0; mf < 4; mf++)
            #pragma unroll
            for (int nf = 0; nf < 4; nf++)
                acc[mf][nf] = __builtin_amdgcn_mfma_f32_16x16x32_bf16(
                    a[mf], b[nf], acc[mf][nf], 0, 0, 0);
    }
}

#define GEMM_LDS_LOOP(A_, B_)                                   \
    __shared__ char smem[65536];                                \
    f32x4 acc[4][4] = {};                                       \
    {                                                           \
        gemm_stage(A_, B_, smem, 0, m_blk, n_blk, 0, wave, lane); \
        __syncthreads();                                        \
        int buf = 0;                                            \
        for (int ks = 0; ks < 8; ks++) {                        \
            if (ks < 7)                                         \
                gemm_stage(A_, B_, smem, buf ^ 1, m_blk, n_blk, (ks + 1) * 64, wave, lane); \
            gemm_compute(smem, buf, wave, lane, acc);           \
            __syncthreads();                                    \
            buf ^= 1;                                           \
        }                                                       \
    }

// qk_t[b][p][o] = sum_c hnT[b][p][c]*wqkv[o][c] + qkv_b[o]; q cols (<512) scaled
__global__ __launch_bounds__(256, 2) void gemm_qk(const bf16* __restrict__ hnT,
                                                  const bf16* __restrict__ wqkv,
                                                  const float* __restrict__ qkv_b,
                                                  bf16* __restrict__ qk_t) {
    int b = blockIdx.z;
    int wave = threadIdx.x >> 6, lane = threadIdx.x & 63;
    int m_blk = blockIdx.x * 128;            // p
    int n_blk = blockIdx.y * 128;            // o
    const bf16* A = hnT + (size_t)b * 1024 * 512;
    GEMM_LDS_LOOP(A, wqkv)
    bf16* out = qk_t + (size_t)b * 1024 * 1024;
    int l15 = lane & 15;
    int col0 = n_blk + (wave & 1) * 64 + l15;
    int row0 = m_blk + (wave >> 1) * 64 + (lane >> 4) * 4;
    #pragma unroll
    for (int nf = 0; nf < 4; nf++) {
        int col = col0 + nf * 16;
        float bias = qkv_b[col];
        float scl = (col < 512) ? SCALE_Q : 1.0f;
        #pragma unroll
        for (int mf = 0; mf < 4; mf++)
            #pragma unroll
            for (int r = 0; r < 4; r++)
                out[(size_t)(row0 + mf * 16 + r) * 1024 + col] =
                    (bf16)((acc[mf][nf][r] + bias) * scl);
    }
}

// vbuf[b][o][p] = sum_c wv[o][c]*hnT[b][p][c] + qkv_b[1024+o]
__global__ __launch_bounds__(256, 2) void gemm_v(const bf16* __restrict__ wv,
                                                 const bf16* __restrict__ hnT,
                                                 const float* __restrict__ qkv_b,
                                                 bf16* __restrict__ vbuf) {
    int b = blockIdx.z;
    int wave = threadIdx.x >> 6, lane = threadIdx.x & 63;
    int m_blk = blockIdx.x * 128;            // o
    int n_blk = blockIdx.y * 128;            // p
    const bf16* Bm = hnT + (size_t)b * 1024 * 512;
    GEMM_LDS_LOOP(wv, Bm)
    bf16* out = vbuf + (size_t)b * 512 * 1024;
    int l15 = lane & 15;
    int col0 = n_blk + (wave & 1) * 64 + l15;
    int row0 = m_blk + (wave >> 1) * 64 + (lane >> 4) * 4;
    #pragma unroll
    for (int mf = 0; mf < 4; mf++)
        #pragma unroll
        for (int r = 0; r < 4; r++) {
            int row = row0 + mf * 16 + r;
            float bias = qkv_b[1024 + row];
            #pragma unroll
            for (int nf = 0; nf < 4; nf++)
                out[(size_t)row * 1024 + col0 + nf * 16] = (bf16)(acc[mf][nf][r] + bias);
        }
}

// out[b][o][i] = sum_c wproj[o][c]*attnT[b][i][c] + proj_b[o] + x[b][o][i]
__global__ __launch_bounds__(256, 2) void gemm_proj(const bf16* __restrict__ wproj,
                                                    const bf16* __restrict__ attnT,
                                                    const float* __restrict__ proj_b,
                                                    const float* __restrict__ x,
                                                    float* __restrict__ out) {
    int b = blockIdx.z;
    int wave = threadIdx.x >> 6, lane = threadIdx.x & 63;
    int m_blk = blockIdx.x * 128;            // o
    int n_blk = blockIdx.y * 128;            // i
    const bf16* Bm = attnT + (size_t)b * 1024 * 512;
    GEMM_LDS_LOOP(wproj, Bm)
    const float* xb = x + (size_t)b * 512 * 1024;
    float* ob = out + (size_t)b * 512 * 1024;
    int l15 = lane & 15;
    int col0 = n_blk + (wave & 1) * 64 + l15;
    int row0 = m_blk + (wave >> 1) * 64 + (lane >> 4) * 4;
    #pragma unroll
    for (int mf = 0; mf < 4; mf++)
        #pragma unroll
        for (int r = 0; r < 4; r++) {
            int row = row0 + mf * 16 + r;
            float bias = proj_b[row];
            #pragma unroll
            for (int nf = 0; nf < 4; nf++) {
                size_t idx = (size_t)row * 1024 + col0 + nf * 16;
                ob[idx] = acc[mf][nf][r] + bias + xb[idx];
            }
        }
}

// ---------------- flash attention, 32x32 MFMA, LDS-staged K/V ----------------
// Grid: 1024 blocks flat = [it 8][bh 128]; XCD-bijective (flat%8 = bh%8).
// 4 waves/block, 32 queries/wave. K/V tiles (64 keys: 8KB K + 8KB V) staged in
// LDS ONCE per block via global_load_lds (coalesced 64B transactions), shared by
// all 4 waves -> ~8x fewer global requests than per-wave register loads, and
// double-buffered so the next tile's loads fly under the current tile's compute.
// XOR swizzle (chunk ^= row&7) pre-applied on the global source; ds_read_b128
// applies the same XOR (proven pattern from gemm_stage/gemm_compute above).
//
// Swapped QK^T: s[jb] = mfma_32x32x16(A=K-rows, B=Q-rows) -> D[j][q]:
//   col = lane&31 = q, row j = (reg&3) + 8*(reg>>2) + 4*(lane>>5)
// P -> PV A-frag fully in-register via cvt_pk_bf16 + permlane32_swap.
// Epilogue: O transposed through LDS (reusing staging space) for coalesced stores.
__global__ __launch_bounds__(256, 4) void attn_kernel(const bf16* __restrict__ qk_t,
                                                      const bf16* __restrict__ vbuf,
                                                      bf16* __restrict__ attnT) {
    int flat = blockIdx.x;
    int it = flat >> 7;          // 0..7 (128-query tiles)
    int bh = flat & 127;
    int b = bh >> 3, h = bh & 7;
    int wave = threadIdx.x >> 6, lane = threadIdx.x & 63;
    int l31 = lane & 31, hi = lane >> 5;
    int i0 = it * 128 + wave * 32;
    const bf16* qkb = qk_t + (size_t)b * 1024 * 1024;
    const bf16* kbase = qkb + 512 + h * 64;                      // K rows (j), stride 1024
    const bf16* vb = vbuf + ((size_t)b * 512 + h * 64) * 1024;   // V rows (d), stride 1024

    __shared__ __align__(16) char smem[32768];  // 2 bufs x (K 8KB + V 8KB); reused for O^T

    // Q as B-operand: col=q=l31, k = 16kc + 8hi + e
    bf16x8 bq[4];
    #pragma unroll
    for (int kc = 0; kc < 4; kc++)
        bq[kc] = ld8(qkb + (size_t)(i0 + l31) * 1024 + h * 64 + kc * 16 + hi * 8);

    f32x16 oacc[2] = {};
    float l_part = 0.f;

    // stage tile j0 into buf: K[64 j][128B], V[64 d][128B], each 8 segs of 1KB,
    // wave w fills segs {w, w+4}; lane covers row seg*8 + (lane>>3), chunk lane&7
    // (source chunk pre-XORed so LDS slot c holds global chunk c^(r&7)).
#define ATTN_STAGE(bufi, j0_)                                                        \
    {                                                                                \
        char* Kl = smem + (bufi) * 16384;                                            \
        char* Vl = Kl + 8192;                                                        \
        _Pragma("unroll")                                                            \
        for (int i = 0; i < 2; i++) {                                                \
            int seg = wave + i * 4;                                                  \
            int r = seg * 8 + (lane >> 3);                                           \
            int cg = (lane & 7) ^ (r & 7);                                           \
            gl_lds16((const char*)(kbase + (size_t)((j0_) + r) * 1024) + cg * 16,    \
                     Kl + seg * 1024);                                               \
            gl_lds16((const char*)(vb + (size_t)r * 1024 + (j0_)) + cg * 16,         \
                     Vl + seg * 1024);                                               \
        }                                                                            \
    }

    ATTN_STAGE(0, 0)
    __syncthreads();
    int buf = 0;

    for (int t = 0; t < 16; t++) {
        if (t < 15) ATTN_STAGE(buf ^ 1, (t + 1) * 64)

        const char* Kl = smem + buf * 16384;
        const char* Vl = Kl + 8192;
        int rx = l31 & 7;   // row&7 for this lane's fragment rows

        // ---- K frags from LDS: row j = 32jb + l31, chunk = 2kc + hi ----
        bf16x8 kf[2][4];
        #pragma unroll
        for (int jb = 0; jb < 2; jb++)
            #pragma unroll
            for (int kc = 0; kc < 4; kc++)
                kf[jb][kc] = *reinterpret_cast<const bf16x8*>(
                    Kl + (jb * 32 + l31) * 128 + (((kc & 1) * 2 + hi + (kc >> 1) * 4) ^ rx) * 16);
        // NOTE: k index = 16kc + 8hi -> byte chunk = (16kc+8hi)/8 = 2kc+hi

        // ---- QK^T (swapped): s[jb] = K[jb-tile] . Q^T ----
        f32x16 s[2] = {};
        #pragma unroll
        for (int kc = 0; kc < 4; kc++) {
            s[0] = __builtin_amdgcn_mfma_f32_32x32x16_bf16(kf[0][kc], bq[kc], s[0], 0, 0, 0);
            s[1] = __builtin_amdgcn_mfma_f32_32x32x16_bf16(kf[1][kc], bq[kc], s[1], 0, 0, 0);
        }

        // ---- V frags from LDS: row d = 32df + l31, k=j chunk = 2ks + hi ----
        bf16x8 vf[2][4];
        #pragma unroll
        for (int df = 0; df < 2; df++)
            #pragma unroll
            for (int ks = 0; ks < 4; ks++)
                vf[df][ks] = *reinterpret_cast<const bf16x8*>(
                    Vl + (df * 32 + l31) * 128 + ((ks * 2 + hi) ^ rx) * 16);

        // ---- exp2 (scale pre-folded into q) + pack to bf16 pairs ----
        unsigned int pk0[2][4], pk1[2][4];
        #pragma unroll
        for (int jb = 0; jb < 2; jb++)
            #pragma unroll
            for (int m = 0; m < 4; m++) {
                float e0 = exp2f(s[jb][m * 4 + 0]);
                float e1 = exp2f(s[jb][m * 4 + 1]);
                float e2 = exp2f(s[jb][m * 4 + 2]);
                float e3 = exp2f(s[jb][m * 4 + 3]);
                l_part += (e0 + e1) + (e2 + e3);
                asm("v_cvt_pk_bf16_f32 %0, %1, %2" : "=v"(pk0[jb][m]) : "v"(e0), "v"(e1));
                asm("v_cvt_pk_bf16_f32 %0, %1, %2" : "=v"(pk1[jb][m]) : "v"(e2), "v"(e3));
            }

        // ---- permlane32_swap: build PV A-frags (4 x bf16x8) in-register ----
        bf16x8 af[4];
        #pragma unroll
        for (int jb = 0; jb < 2; jb++)
            #pragma unroll
            for (int tt = 0; tt < 2; tt++) {
                unsigned int a0 = pk0[jb][tt * 2], b0 = pk0[jb][tt * 2 + 1];
                unsigned int a1 = pk1[jb][tt * 2], b1 = pk1[jb][tt * 2 + 1];
                asm("v_permlane32_swap_b32 %0, %1" : "+v"(a0), "+v"(b0));
                asm("v_permlane32_swap_b32 %0, %1" : "+v"(a1), "+v"(b1));
                u32x4 w = {a0, a1, b0, b1};   // e01, e23, e45, e67
                af[jb * 2 + tt] = __builtin_bit_cast(bf16x8, w);
            }

        // ---- PV: oacc[df] += P . V^T ----
        #pragma unroll
        for (int ks = 0; ks < 4; ks++) {
            oacc[0] = __builtin_amdgcn_mfma_f32_32x32x16_bf16(af[ks], vf[0][ks], oacc[0], 0, 0, 0);
            oacc[1] = __builtin_amdgcn_mfma_f32_32x32x16_bf16(af[ks], vf[1][ks], oacc[1], 0, 0, 0);
        }

        __syncthreads();
        buf ^= 1;
    }
#undef ATTN_STAGE

    // ---- softmax denominator (lane (0,q)+(1,q) cover all j for query q) ----
    float lsum = l_part + __shfl_xor(l_part, 32);
    float inv = 1.f / lsum;

    // ---- O^T via LDS transpose for coalesced stores ----
    // O_l[128 i][72 c-stride] bf16 (144B rows, 16B aligned; wave w rows w*32..+31)
    bf16* O_l = (bf16*)smem;
    #pragma unroll
    for (int reg = 0; reg < 16; reg++) {
        int qrow = (reg & 3) + 8 * (reg >> 2) + 4 * hi;
        float iv = __shfl(inv, qrow);   // inv for query qrow (lives in lane qrow)
        O_l[(wave * 32 + qrow) * 72 + l31]      = (bf16)(oacc[0][reg] * iv);
        O_l[(wave * 32 + qrow) * 72 + 32 + l31] = (bf16)(oacc[1][reg] * iv);
    }
    __syncthreads();
    // readout: thread t -> row i=t>>1, half = t&1 (32 cols = 64B)
    {
        int tt = threadIdx.x;
        int il = tt >> 1, half = tt & 1;
        const bf16* lsrc = O_l + il * 72 + half * 32;
        bf16* gdst = attnT + ((size_t)b * 1024 + it * 128 + il) * 512 + h * 64 + half * 32;
        #pragma unroll
        for (int k = 0; k < 4; k++)
            *reinterpret_cast<bf16x8*>(gdst + k * 8) =
                *reinterpret_cast<const bf16x8*>(lsrc + k * 8);
    }
}

extern "C" void kernel_launch(void* const* d_in, const int* in_sizes, int n_in,
                              void* d_out, int out_size, void* d_ws, size_t ws_size,
                              hipStream_t stream) {
    (void)in_sizes; (void)n_in; (void)out_size; (void)ws_size;
    const float* x      = (const float*)d_in[0];
    const float* norm_w = (const float*)d_in[1];
    const float* norm_b = (const float*)d_in[2];
    const float* qkv_w  = (const float*)d_in[3];
    const float* qkv_b  = (const float*)d_in[4];
    const float* proj_w = (const float*)d_in[5];
    const float* proj_b = (const float*)d_in[6];
    float* out = (float*)d_out;

    // workspace layout (~86 MB)
    char* w = (char*)d_ws;
    bf16* wqkv  = (bf16*)w;                        // 1536*512
    bf16* wproj = wqkv + (size_t)1536 * 512;       // 512*512
    float2* stats = (float2*)(wproj + (size_t)512 * 512);  // 128
    bf16* hnT   = (bf16*)((char*)stats + 1024);    // [16][1024][512]
    bf16* qk_t  = hnT + (size_t)16 * 1024 * 512;   // [16][1024][1024]
    bf16* vbuf  = qk_t + (size_t)16 * 1024 * 1024; // [16][512][1024]
    bf16* attnT = vbuf + (size_t)16 * 512 * 1024;  // [16][1024][512]

    cvt_fp32_bf16<<<768, 256, 0, stream>>>(qkv_w, wqkv, 1536 * 512);
    cvt_fp32_bf16<<<256, 256, 0, stream>>>(proj_w, wproj, 512 * 512);
    gn_stats<<<128, 256, 0, stream>>>(x, stats);
    gn_apply_t<<<dim3(16, 8, 16), 256, 0, stream>>>(x, norm_w, norm_b, stats, hnT);
    gemm_qk<<<dim3(8, 8, 16), 256, 0, stream>>>(hnT, wqkv, qkv_b, qk_t);
    gemm_v<<<dim3(4, 8, 16), 256, 0, stream>>>(wqkv + (size_t)1024 * 512, hnT, qkv_b, vbuf);
    attn_kernel<<<1024, 256, 0, stream>>>(qk_t, vbuf, attnT);
    gemm_proj<<<dim3(4, 8, 16), 256, 0, stream>>>(wproj, attnT, proj_b, x, out);
}

// Round 7
// 147.620 us; speedup vs baseline: 2.9402x; 1.0015x over previous
//
#include <hip/hip_runtime.h>
#include <hip/hip_bf16.h>

// AttentionBlock: groupnorm -> qkv conv1x1 -> MHA (8 heads, hd=64) -> proj -> residual
// B=16, C=512, H=W=32 (HW=1024). All GEMM-shaped work in bf16 MFMA, fp32 accum.

typedef __bf16 bf16;
typedef __attribute__((ext_vector_type(8))) __bf16 bf16x8;
typedef __attribute__((ext_vector_type(4))) float f32x4;
typedef __attribute__((ext_vector_type(16))) float f32x16;
typedef __attribute__((ext_vector_type(4))) unsigned int u32x4;

#define SCALE_Q 0.18033688f  // 0.125 * log2(e), folded into q at gemm epilogue

__device__ __forceinline__ bf16x8 ld8(const bf16* p) {
    return *reinterpret_cast<const bf16x8*>(p);
}

__device__ __forceinline__ void gl_lds16(const void* g, void* l) {
    __builtin_amdgcn_global_load_lds(
        (const __attribute__((address_space(1))) void*)g,
        (__attribute__((address_space(3))) void*)l, 16, 0, 0);
}

// ---------------- weight fp32 -> bf16 (both weights, one launch) ----------------
// dst layout: [wqkv 1536*512][wproj 512*512] contiguous. 1024 blocks x 256 thr x 4 elem.
__global__ __launch_bounds__(256) void cvt_weights(const float* __restrict__ qkv_w,
                                                   const float* __restrict__ proj_w,
                                                   bf16* __restrict__ dst) {
    const int N1 = 1536 * 512;
    int i = (blockIdx.x * 256 + threadIdx.x) * 4;
    float4 f = (i < N1) ? *reinterpret_cast<const float4*>(qkv_w + i)
                        : *reinterpret_cast<const float4*>(proj_w + (i - N1));
    dst[i + 0] = (bf16)f.x;
    dst[i + 1] = (bf16)f.y;
    dst[i + 2] = (bf16)f.z;
    dst[i + 3] = (bf16)f.w;
}

// ---------------- fused groupnorm: stats + normalize + transpose ----------------
// One block per (b,g). Pass 1: stream 256KB computing sum/sumsq (HBM).
// Pass 2: re-read (L2-hot: 16 blocks/XCD x 256KB = 4MB = one XCD L2) through a
// 64x65 LDS transpose tile, write hnT[b][p][c] bf16. Saves a full 64MB HBM pass
// vs separate stats+apply kernels.
__global__ __launch_bounds__(256) void gn_fused(const float* __restrict__ x,
                                                const float* __restrict__ gamma,
                                                const float* __restrict__ beta,
                                                bf16* __restrict__ hnT) {
    int bg = blockIdx.x;
    int b = bg >> 3, g = bg & 7;
    const float* base = x + (size_t)bg * 65536;
    int t = threadIdx.x;
    int wave = t >> 6, lane = t & 63;

    float s = 0.f, sq = 0.f;
    for (int i = t * 4; i < 65536; i += 256 * 4) {
        float4 f = *reinterpret_cast<const float4*>(base + i);
        s += f.x + f.y + f.z + f.w;
        sq += f.x * f.x + f.y * f.y + f.z * f.z + f.w * f.w;
    }
    #pragma unroll
    for (int off = 32; off > 0; off >>= 1) {
        s += __shfl_down(s, off);
        sq += __shfl_down(sq, off);
    }
    __shared__ float ls[4], lq[4];
    __shared__ float2 st;
    if (lane == 0) { ls[wave] = s; lq[wave] = sq; }
    __syncthreads();
    if (t == 0) {
        s = ls[0] + ls[1] + ls[2] + ls[3];
        sq = lq[0] + lq[1] + lq[2] + lq[3];
        float mean = s * (1.f / 65536.f);
        float var = sq * (1.f / 65536.f) - mean * mean;
        st = make_float2(mean, rsqrtf(var + 1e-5f));
    }
    __syncthreads();
    float mean = st.x, rstd = st.y;

    __shared__ float tile[64][65];
    int cl = t & 63;
    float ga = gamma[g * 64 + cl] * rstd;
    float be = beta[g * 64 + cl] - mean * ga;   // v*ga + be == (v-mean)*rstd*gamma+beta
    for (int pt = 0; pt < 16; pt++) {
        const float* xb = base + pt * 64;
        #pragma unroll
        for (int r = 0; r < 16; r++) {
            int crow = r * 4 + (t >> 6);
            tile[crow][t & 63] = xb[(size_t)crow * 1024 + (t & 63)];
        }
        __syncthreads();
        bf16* ob = hnT + ((size_t)b * 1024 + pt * 64) * 512 + g * 64 + cl;
        #pragma unroll
        for (int r = 0; r < 16; r++) {
            int pl = r * 4 + (t >> 6);
            ob[(size_t)pl * 512] = (bf16)(tile[cl][pl] * ga + be);
        }
        __syncthreads();
    }
}

// ---------------- staged NT-GEMM core (m97 structure) ----------------
// 128x128 tile, BK=64, K=512 (8 k-steps), 4 waves (2x2 of 64x64).
// LDS: 2 bufs x (A 16KB + B 16KB) = 64KB. global_load_lds width=16, with
// pre-swizzled global source so LDS[r][chunk c] holds global chunk c^(r&7);
// ds_read_b128 applies the same XOR -> conflict-free minimum (8 lanes/span).
__device__ __forceinline__ void gemm_stage(const bf16* __restrict__ A,
                                           const bf16* __restrict__ B,
                                           char* smem, int buf,
                                           int m_blk, int n_blk, int k0,
                                           int wave, int lane) {
    char* Al = smem + buf * 32768;
    char* Bl = Al + 16384;
    #pragma unroll
    for (int i = 0; i < 4; i++) {
        int seg = i * 4 + wave;              // 16 segs of 1KB per 16KB tile
        int r = seg * 8 + (lane >> 3);       // tile row this lane fills
        int cg = (lane & 7) ^ (r & 7);       // pre-swizzled source chunk
        gl_lds16((const char*)(A + (size_t)(m_blk + r) * 512 + k0) + cg * 16,
                 Al + seg * 1024);
        gl_lds16((const char*)(B + (size_t)(n_blk + r) * 512 + k0) + cg * 16,
                 Bl + seg * 1024);
    }
}

__device__ __forceinline__ void gemm_compute(const char* smem, int buf,
                                             int wave, int lane,
                                             f32x4 (&acc)[4][4]) {
    const char* Al = smem + buf * 32768;
    const char* Bl = Al + 16384;
    int l15 = lane & 15, hi = lane >> 4;
    int mb = (wave >> 1) * 64, nb = (wave & 1) * 64;
    #pragma unroll
    for (int kc = 0; kc < 2; kc++) {
        int ck = kc * 4 + hi;                // 16B chunk of the 64-wide k-slab
        bf16x8 a[4], b[4];
        #pragma unroll
        for (int mf = 0; mf < 4; mf++) {
            int row = mb + mf * 16 + l15;
            a[mf] = *reinterpret_cast<const bf16x8*>(Al + row * 128 + (ck ^ (row & 7)) * 16);
        }
        #pragma unroll
        for (int nf = 0; nf < 4; nf++) {
            int row = nb + nf * 16 + l15;
            b[nf] = *reinterpret_cast<const bf16x8*>(Bl + row * 128 + (ck ^ (row & 7)) * 16);
        }
        #pragma unroll
        for (int mf = 0; mf < 4; mf++)
            #pragma unroll
            for (int nf = 0; nf < 4; nf++)
                acc[mf][nf] = __builtin_amdgcn_mfma_f32_16x16x32_bf16(
                    a[mf], b[nf], acc[mf][nf], 0, 0, 0);
    }
}

#define GEMM_LDS_LOOP(A_, B_, SMEM_)                            \
    f32x4 acc[4][4] = {};                                       \
    {                                                           \
        gemm_stage(A_, B_, SMEM_, 0, m_blk, n_blk, 0, wave, lane); \
        __syncthreads();                                        \
        int buf = 0;                                            \
        for (int ks = 0; ks < 8; ks++) {                        \
            if (ks < 7)                                         \
                gemm_stage(A_, B_, SMEM_, buf ^ 1, m_blk, n_blk, (ks + 1) * 64, wave, lane); \
            gemm_compute(SMEM_, buf, wave, lane, acc);          \
            __syncthreads();                                    \
            buf ^= 1;                                           \
        }                                                       \
    }

// Fused QKV GEMM, one launch. blockIdx.y < 8: qk path
//   qk_t[b][p][o] = sum_c hnT[b][p][c]*wqkv[o][c] + qkv_b[o]  (q cols scaled)
// blockIdx.y >= 8: v path
//   vbuf[b][o][p] = sum_c wv[o][c]*hnT[b][p][c] + qkv_b[1024+o]
__global__ __launch_bounds__(256, 2) void gemm_qkv(const bf16* __restrict__ hnT,
                                                   const bf16* __restrict__ wqkv,
                                                   const float* __restrict__ qkv_b,
                                                   bf16* __restrict__ qk_t,
                                                   bf16* __restrict__ vbuf) {
    __shared__ char smem[65536];
    int b = blockIdx.z;
    int wave = threadIdx.x >> 6, lane = threadIdx.x & 63;
    int l15 = lane & 15;
    int y = blockIdx.y;
    if (y < 8) {
        int m_blk = blockIdx.x * 128;        // p
        int n_blk = y * 128;                 // o
        const bf16* A = hnT + (size_t)b * 1024 * 512;
        GEMM_LDS_LOOP(A, wqkv, smem)
        bf16* out = qk_t + (size_t)b * 1024 * 1024;
        int col0 = n_blk + (wave & 1) * 64 + l15;
        int row0 = m_blk + (wave >> 1) * 64 + (lane >> 4) * 4;
        #pragma unroll
        for (int nf = 0; nf < 4; nf++) {
            int col = col0 + nf * 16;
            float bias = qkv_b[col];
            float scl = (col < 512) ? SCALE_Q : 1.0f;
            #pragma unroll
            for (int mf = 0; mf < 4; mf++)
                #pragma unroll
                for (int r = 0; r < 4; r++)
                    out[(size_t)(row0 + mf * 16 + r) * 1024 + col] =
                        (bf16)((acc[mf][nf][r] + bias) * scl);
        }
    } else {
        int m_blk = (y - 8) * 128;           // o
        int n_blk = blockIdx.x * 128;        // p
        const bf16* A = wqkv + (size_t)1024 * 512;   // wv
        const bf16* Bm = hnT + (size_t)b * 1024 * 512;
        GEMM_LDS_LOOP(A, Bm, smem)
        bf16* out = vbuf + (size_t)b * 512 * 1024;
        int col0 = n_blk + (wave & 1) * 64 + l15;
        int row0 = m_blk + (wave >> 1) * 64 + (lane >> 4) * 4;
        #pragma unroll
        for (int mf = 0; mf < 4; mf++)
            #pragma unroll
            for (int r = 0; r < 4; r++) {
                int row = row0 + mf * 16 + r;
                float bias = qkv_b[1024 + row];
                #pragma unroll
                for (int nf = 0; nf < 4; nf++)
                    out[(size_t)row * 1024 + col0 + nf * 16] = (bf16)(acc[mf][nf][r] + bias);
            }
    }
}

// out[b][o][i] = sum_c wproj[o][c]*attnT[b][i][c] + proj_b[o] + x[b][o][i]
__global__ __launch_bounds__(256, 2) void gemm_proj(const bf16* __restrict__ wproj,
                                                    const bf16* __restrict__ attnT,
                                                    const float* __restrict__ proj_b,
                                                    const float* __restrict__ x,
                                                    float* __restrict__ out) {
    __shared__ char smem[65536];
    int b = blockIdx.z;
    int wave = threadIdx.x >> 6, lane = threadIdx.x & 63;
    int m_blk = blockIdx.x * 128;            // o
    int n_blk = blockIdx.y * 128;            // i
    const bf16* Bm = attnT + (size_t)b * 1024 * 512;
    GEMM_LDS_LOOP(wproj, Bm, smem)
    const float* xb = x + (size_t)b * 512 * 1024;
    float* ob = out + (size_t)b * 512 * 1024;
    int l15 = lane & 15;
    int col0 = n_blk + (wave & 1) * 64 + l15;
    int row0 = m_blk + (wave >> 1) * 64 + (lane >> 4) * 4;
    #pragma unroll
    for (int mf = 0; mf < 4; mf++)
        #pragma unroll
        for (int r = 0; r < 4; r++) {
            int row = row0 + mf * 16 + r;
            float bias = proj_b[row];
            #pragma unroll
            for (int nf = 0; nf < 4; nf++) {
                size_t idx = (size_t)row * 1024 + col0 + nf * 16;
                ob[idx] = acc[mf][nf][r] + bias + xb[idx];
            }
        }
}

// ---------------- flash attention, 32x32 MFMA, LDS-staged K/V ----------------
// Grid: 1024 blocks flat = [it 8][bh 128]; XCD-bijective (flat%8 = bh%8).
// 4 waves/block, 32 queries/wave. K/V tiles staged in LDS once per block via
// global_load_lds, double-buffered. Counted-vmcnt pipeline (T4): each wave waits
// vmcnt(4) (its own previous-tile stage loads) instead of the vmcnt(0) drain that
// __syncthreads() would emit, so next-tile DMA stays in flight across barriers.
// Race-freedom: barrier#1 = all waves done reading the buffer being overwritten;
// per-wave vmcnt(4) + barrier#2 = everyone's stage(t) landed before any read.
__global__ __launch_bounds__(256, 4) void attn_kernel(const bf16* __restrict__ qk_t,
                                                      const bf16* __restrict__ vbuf,
                                                      bf16* __restrict__ attnT) {
    int flat = blockIdx.x;
    int it = flat >> 7;          // 0..7 (128-query tiles)
    int bh = flat & 127;
    int b = bh >> 3, h = bh & 7;
    int wave = threadIdx.x >> 6, lane = threadIdx.x & 63;
    int l31 = lane & 31, hi = lane >> 5;
    int i0 = it * 128 + wave * 32;
    const bf16* qkb = qk_t + (size_t)b * 1024 * 1024;
    const bf16* kbase = qkb + 512 + h * 64;                      // K rows (j), stride 1024
    const bf16* vb = vbuf + ((size_t)b * 512 + h * 64) * 1024;   // V rows (d), stride 1024

    __shared__ __align__(16) char smem[32768];  // 2 bufs x (K 8KB + V 8KB); reused for O^T

    // Q as B-operand: col=q=l31, k = 16kc + 8hi + e
    bf16x8 bq[4];
    #pragma unroll
    for (int kc = 0; kc < 4; kc++)
        bq[kc] = ld8(qkb + (size_t)(i0 + l31) * 1024 + h * 64 + kc * 16 + hi * 8);

    f32x16 oacc[2] = {};
    float l_part = 0.f;

#define ATTN_STAGE(bufi, j0_)                                                        \
    {                                                                                \
        char* Kl = smem + (bufi) * 16384;                                            \
        char* Vl = Kl + 8192;                                                        \
        _Pragma("unroll")                                                            \
        for (int i = 0; i < 2; i++) {                                                \
            int seg = wave + i * 4;                                                  \
            int r = seg * 8 + (lane >> 3);                                           \
            int cg = (lane & 7) ^ (r & 7);                                           \
            gl_lds16((const char*)(kbase + (size_t)((j0_) + r) * 1024) + cg * 16,    \
                     Kl + seg * 1024);                                               \
            gl_lds16((const char*)(vb + (size_t)r * 1024 + (j0_)) + cg * 16,         \
                     Vl + seg * 1024);                                               \
        }                                                                            \
    }

    ATTN_STAGE(0, 0)                 // 4 loads in flight
    int buf = 0;

    for (int t = 0; t < 16; t++) {
        // barrier#1: everyone finished reading buf^1's old contents (iter t-1)
        asm volatile("" ::: "memory");
        __builtin_amdgcn_s_barrier();
        if (t < 15) {
            ATTN_STAGE(buf ^ 1, (t + 1) * 64)                    // +4 loads
            asm volatile("s_waitcnt vmcnt(4)" ::: "memory");     // stage(t) landed
        } else {
            asm volatile("s_waitcnt vmcnt(0)" ::: "memory");
        }
        __builtin_amdgcn_s_barrier();                            // all waves' stage(t) landed
        asm volatile("" ::: "memory");

        const char* Kl = smem + buf * 16384;
        const char* Vl = Kl + 8192;
        int rx = l31 & 7;   // row&7 for this lane's fragment rows

        // ---- K frags from LDS: row j = 32jb + l31, k chunk = 2kc + hi ----
        bf16x8 kf[2][4];
        #pragma unroll
        for (int jb = 0; jb < 2; jb++)
            #pragma unroll
            for (int kc = 0; kc < 4; kc++)
                kf[jb][kc] = *reinterpret_cast<const bf16x8*>(
                    Kl + (jb * 32 + l31) * 128 + ((kc * 2 + hi) ^ rx) * 16);

        // ---- QK^T (swapped): s[jb] = K[jb-tile] . Q^T ----
        f32x16 s[2] = {};
        #pragma unroll
        for (int kc = 0; kc < 4; kc++) {
            s[0] = __builtin_amdgcn_mfma_f32_32x32x16_bf16(kf[0][kc], bq[kc], s[0], 0, 0, 0);
            s[1] = __builtin_amdgcn_mfma_f32_32x32x16_bf16(kf[1][kc], bq[kc], s[1], 0, 0, 0);
        }

        // ---- V frags from LDS: row d = 32df + l31, k=j chunk = 2ks + hi ----
        bf16x8 vf[2][4];
        #pragma unroll
        for (int df = 0; df < 2; df++)
            #pragma unroll
            for (int ks = 0; ks < 4; ks++)
                vf[df][ks] = *reinterpret_cast<const bf16x8*>(
                    Vl + (df * 32 + l31) * 128 + ((ks * 2 + hi) ^ rx) * 16);

        // ---- exp2 (scale pre-folded into q) + pack to bf16 pairs ----
        unsigned int pk0[2][4], pk1[2][4];
        #pragma unroll
        for (int jb = 0; jb < 2; jb++)
            #pragma unroll
            for (int m = 0; m < 4; m++) {
                float e0 = exp2f(s[jb][m * 4 + 0]);
                float e1 = exp2f(s[jb][m * 4 + 1]);
                float e2 = exp2f(s[jb][m * 4 + 2]);
                float e3 = exp2f(s[jb][m * 4 + 3]);
                l_part += (e0 + e1) + (e2 + e3);
                asm("v_cvt_pk_bf16_f32 %0, %1, %2" : "=v"(pk0[jb][m]) : "v"(e0), "v"(e1));
                asm("v_cvt_pk_bf16_f32 %0, %1, %2" : "=v"(pk1[jb][m]) : "v"(e2), "v"(e3));
            }

        // ---- permlane32_swap: build PV A-frags (4 x bf16x8) in-register ----
        bf16x8 af[4];
        #pragma unroll
        for (int jb = 0; jb < 2; jb++)
            #pragma unroll
            for (int tt = 0; tt < 2; tt++) {
                unsigned int a0 = pk0[jb][tt * 2], b0 = pk0[jb][tt * 2 + 1];
                unsigned int a1 = pk1[jb][tt * 2], b1 = pk1[jb][tt * 2 + 1];
                asm("v_permlane32_swap_b32 %0, %1" : "+v"(a0), "+v"(b0));
                asm("v_permlane32_swap_b32 %0, %1" : "+v"(a1), "+v"(b1));
                u32x4 w = {a0, a1, b0, b1};   // e01, e23, e45, e67
                af[jb * 2 + tt] = __builtin_bit_cast(bf16x8, w);
            }

        // ---- PV: oacc[df] += P . V^T ----
        #pragma unroll
        for (int ks = 0; ks < 4; ks++) {
            oacc[0] = __builtin_amdgcn_mfma_f32_32x32x16_bf16(af[ks], vf[0][ks], oacc[0], 0, 0, 0);
            oacc[1] = __builtin_amdgcn_mfma_f32_32x32x16_bf16(af[ks], vf[1][ks], oacc[1], 0, 0, 0);
        }

        buf ^= 1;
    }
#undef ATTN_STAGE

    // ---- softmax denominator (lane (0,q)+(1,q) cover all j for query q) ----
    float lsum = l_part + __shfl_xor(l_part, 32);
    float inv = 1.f / lsum;

    __syncthreads();   // all waves done with K/V LDS before O^T reuse

    // ---- O^T via LDS transpose for coalesced stores ----
    bf16* O_l = (bf16*)smem;
    #pragma unroll
    for (int reg = 0; reg < 16; reg++) {
        int qrow = (reg & 3) + 8 * (reg >> 2) + 4 * hi;
        float iv = __shfl(inv, qrow);   // inv for query qrow (lives in lane qrow)
        O_l[(wave * 32 + qrow) * 72 + l31]      = (bf16)(oacc[0][reg] * iv);
        O_l[(wave * 32 + qrow) * 72 + 32 + l31] = (bf16)(oacc[1][reg] * iv);
    }
    __syncthreads();
    {
        int tt = threadIdx.x;
        int il = tt >> 1, half = tt & 1;
        const bf16* lsrc = O_l + il * 72 + half * 32;
        bf16* gdst = attnT + ((size_t)b * 1024 + it * 128 + il) * 512 + h * 64 + half * 32;
        #pragma unroll
        for (int k = 0; k < 4; k++)
            *reinterpret_cast<bf16x8*>(gdst + k * 8) =
                *reinterpret_cast<const bf16x8*>(lsrc + k * 8);
    }
}

extern "C" void kernel_launch(void* const* d_in, const int* in_sizes, int n_in,
                              void* d_out, int out_size, void* d_ws, size_t ws_size,
                              hipStream_t stream) {
    (void)in_sizes; (void)n_in; (void)out_size; (void)ws_size;
    const float* x      = (const float*)d_in[0];
    const float* norm_w = (const float*)d_in[1];
    const float* norm_b = (const float*)d_in[2];
    const float* qkv_w  = (const float*)d_in[3];
    const float* qkv_b  = (const float*)d_in[4];
    const float* proj_w = (const float*)d_in[5];
    const float* proj_b = (const float*)d_in[6];
    float* out = (float*)d_out;

    // workspace layout (~86 MB)
    char* w = (char*)d_ws;
    bf16* wqkv  = (bf16*)w;                        // 1536*512
    bf16* wproj = wqkv + (size_t)1536 * 512;       // 512*512 (contiguous after wqkv)
    bf16* hnT   = wproj + (size_t)512 * 512;       // [16][1024][512]
    bf16* qk_t  = hnT + (size_t)16 * 1024 * 512;   // [16][1024][1024]
    bf16* vbuf  = qk_t + (size_t)16 * 1024 * 1024; // [16][512][1024]
    bf16* attnT = vbuf + (size_t)16 * 512 * 1024;  // [16][1024][512]

    cvt_weights<<<1024, 256, 0, stream>>>(qkv_w, proj_w, wqkv);
    gn_fused<<<128, 256, 0, stream>>>(x, norm_w, norm_b, hnT);
    gemm_qkv<<<dim3(8, 12, 16), 256, 0, stream>>>(hnT, wqkv, qkv_b, qk_t, vbuf);
    attn_kernel<<<1024, 256, 0, stream>>>(qk_t, vbuf, attnT);
    gemm_proj<<<dim3(4, 8, 16), 256, 0, stream>>>(wproj, attnT, proj_b, x, out);
}